// Round 4
// baseline (239.879 us; speedup 1.0000x reference)
//
#include <hip/hip_runtime.h>
#include <hip/hip_bf16.h>

#define N_NODES 8192
#define DEG     16
#define F_IN    1024
#define F_OUT   128
#define NH      8

typedef __bf16 bf16x8 __attribute__((ext_vector_type(8)));
typedef float  f32x4  __attribute__((ext_vector_type(4)));

__device__ __forceinline__ float bf2f(unsigned short u) {
    union { unsigned int i; float f; } v;
    v.i = ((unsigned int)u) << 16;
    return v.f;
}

// fp32 -> bf16 with round-to-nearest-even (inputs are finite)
__device__ __forceinline__ unsigned short f2bf(float f) {
    union { float f; unsigned int u; } v; v.f = f;
    unsigned int u = v.u + 0x7FFFu + ((v.u >> 16) & 1u);
    return (unsigned short)(u >> 16);
}

// ---------------------------------------------------------------------------
// Runtime input-dtype probe. For each sampled 32-bit word, bits[14:7] are:
//   - bf16 data: the exponent field of element 2i  -> in [100,140] for any
//     normal-ish value (|x| in [2^-27, 2^12]) -> ~64/64 hits
//   - fp32 data: mantissa bits 14..7 -> ~uniform  -> ~10/64 hits
// Wave-uniform result (all threads sample identical addresses).
// ---------------------------------------------------------------------------
__device__ __forceinline__ int detect_bf16(const unsigned int* __restrict__ w) {
    int hits = 0;
#pragma unroll
    for (int i = 0; i < 64; ++i) {
        unsigned int x = w[i * 131 + 17];
        int e = (x >> 7) & 0xFF;
        hits += (e >= 100 && e <= 140) ? 1 : 0;
    }
    return hits > 32;
}

// ---------------------------------------------------------------------------
// Kernel 1: per-head GEMM  h[h][n][o] = features[n][:] @ W[h][:][o] + bW[h][o]
// 128x128 tile, BK=64, mfma_f32_16x16x32_bf16, fp32 acc, bf16 store to ws.
// Dual staging path: bf16 inputs copied, fp32 inputs converted on the fly.
// ---------------------------------------------------------------------------
__global__ __launch_bounds__(256) void gat_gemm(
    const void* __restrict__ feat,     // [N, F_IN] bf16 OR fp32
    const void* __restrict__ W,        // [H, F_IN, F_OUT] bf16 OR fp32
    const void* __restrict__ bW,       // [H, F_OUT] bf16 OR fp32
    __hip_bfloat16* __restrict__ hbuf) // [H, N, F_OUT] bf16 (ws, 16 MB exact)
{
    const int isbf = detect_bf16((const unsigned int*)feat);

    const int h   = blockIdx.y;
    const int n0  = blockIdx.x * 128;
    const int tid = threadIdx.x;

    __shared__ __align__(16) unsigned short As[128][72];  // [node][k]
    __shared__ __align__(16) unsigned short Bs[128][72];  // [o][k]

    const int lane = tid & 63;
    const int wave = tid >> 6;
    const int quad = lane >> 4;
    const int l16  = lane & 15;

    f32x4 acc[2][8];
#pragma unroll
    for (int i = 0; i < 2; ++i)
#pragma unroll
        for (int j = 0; j < 8; ++j) acc[i][j] = (f32x4)0.f;

    for (int k0 = 0; k0 < F_IN; k0 += 64) {
        if (isbf) {
            const unsigned short* fbase = (const unsigned short*)feat + (size_t)n0 * F_IN;
            const unsigned short* wsrc  = (const unsigned short*)W +
                                          (size_t)h * F_IN * F_OUT + (size_t)k0 * F_OUT;
            // A tile: 128 nodes x 64 k, k-contiguous -> 16B copies
#pragma unroll
            for (int t = 0; t < 4; ++t) {
                int c = t * 256 + tid, row = c >> 3, kc = c & 7;
                *(uint4*)&As[row][kc * 8] =
                    *(const uint4*)&fbase[row * F_IN + k0 + kc * 8];
            }
            // B tile: W[k][o] -> Bs[o][k], k-pairs packed, rotated writes
#pragma unroll
            for (int t = 0; t < 2; ++t) {
                int c = t * 256 + tid;
                int kr2 = c >> 4, m = c & 15, oc = m * 8;
                uint4 w0 = *(const uint4*)&wsrc[(2 * kr2    ) * F_OUT + oc];
                uint4 w1 = *(const uint4*)&wsrc[(2 * kr2 + 1) * F_OUT + oc];
                const unsigned short* p0 = (const unsigned short*)&w0;
                const unsigned short* p1 = (const unsigned short*)&w1;
#pragma unroll
                for (int j = 0; j < 8; ++j) {
                    int i = (j + m) & 7;
                    unsigned int val = (unsigned int)p0[i] | ((unsigned int)p1[i] << 16);
                    *(unsigned int*)&Bs[oc + i][2 * kr2] = val;
                }
            }
        } else {
            const float* fbase = (const float*)feat + (size_t)n0 * F_IN;
            const float* wsrc  = (const float*)W +
                                 (size_t)h * F_IN * F_OUT + (size_t)k0 * F_OUT;
#pragma unroll
            for (int t = 0; t < 4; ++t) {
                int c = t * 256 + tid, row = c >> 3, kc = c & 7;
                const float* src = &fbase[row * F_IN + k0 + kc * 8];
                float4 u0 = *(const float4*)src;
                float4 u1 = *(const float4*)(src + 4);
                unsigned short s[8] = { f2bf(u0.x), f2bf(u0.y), f2bf(u0.z), f2bf(u0.w),
                                        f2bf(u1.x), f2bf(u1.y), f2bf(u1.z), f2bf(u1.w) };
                *(uint4*)&As[row][kc * 8] = *(const uint4*)s;
            }
#pragma unroll
            for (int t = 0; t < 2; ++t) {
                int c = t * 256 + tid;
                int kr2 = c >> 4, m = c & 15, oc = m * 8;
                const float* r0 = &wsrc[(2 * kr2    ) * F_OUT + oc];
                const float* r1 = &wsrc[(2 * kr2 + 1) * F_OUT + oc];
                float4 e0 = *(const float4*)r0, e1 = *(const float4*)(r0 + 4);
                float4 o0 = *(const float4*)r1, o1 = *(const float4*)(r1 + 4);
                unsigned short p0[8] = { f2bf(e0.x), f2bf(e0.y), f2bf(e0.z), f2bf(e0.w),
                                         f2bf(e1.x), f2bf(e1.y), f2bf(e1.z), f2bf(e1.w) };
                unsigned short p1[8] = { f2bf(o0.x), f2bf(o0.y), f2bf(o0.z), f2bf(o0.w),
                                         f2bf(o1.x), f2bf(o1.y), f2bf(o1.z), f2bf(o1.w) };
#pragma unroll
                for (int j = 0; j < 8; ++j) {
                    int i = (j + m) & 7;
                    unsigned int val = (unsigned int)p0[i] | ((unsigned int)p1[i] << 16);
                    *(unsigned int*)&Bs[oc + i][2 * kr2] = val;
                }
            }
        }
        __syncthreads();

#pragma unroll
        for (int ks = 0; ks < 2; ++ks) {
            const int kk = ks * 32 + quad * 8;
            bf16x8 af[2], bfr[8];
#pragma unroll
            for (int rt = 0; rt < 2; ++rt)
                af[rt] = *(const bf16x8*)&As[wave * 32 + rt * 16 + l16][kk];
#pragma unroll
            for (int ct = 0; ct < 8; ++ct)
                bfr[ct] = *(const bf16x8*)&Bs[ct * 16 + l16][kk];
#pragma unroll
            for (int rt = 0; rt < 2; ++rt)
#pragma unroll
                for (int ct = 0; ct < 8; ++ct)
                    acc[rt][ct] = __builtin_amdgcn_mfma_f32_16x16x32_bf16(
                        af[rt], bfr[ct], acc[rt][ct], 0, 0, 0);
        }
        __syncthreads();
    }

    // epilogue: D col(=o) = lane&15, row(=node) = quad*4 + reg (m89/m91)
#pragma unroll
    for (int ct = 0; ct < 8; ++ct) {
        const int col = ct * 16 + l16;
        const float bwv = isbf ? bf2f(((const unsigned short*)bW)[h * F_OUT + col])
                               : ((const float*)bW)[h * F_OUT + col];
#pragma unroll
        for (int rt = 0; rt < 2; ++rt) {
            const int nrow = n0 + wave * 32 + rt * 16 + quad * 4;
            __hip_bfloat16* dst = hbuf + ((size_t)h * N_NODES + nrow) * F_OUT + col;
#pragma unroll
            for (int r = 0; r < 4; ++r)
                dst[(size_t)r * F_OUT] = __float2bfloat16(acc[rt][ct][r] + bwv);
        }
    }
}

// ---------------------------------------------------------------------------
// Kernel 2: fused scores + softmax + aggregate. One wave per (node, head).
// hbuf is always bf16 (internal); a/ba/out follow detected dtype.
// ---------------------------------------------------------------------------
__global__ __launch_bounds__(256) void gat_aggr(
    const __hip_bfloat16* __restrict__ hbuf,   // [H, N, F_OUT] bf16
    const int* __restrict__ adj,               // [N, DEG] i32
    const void* __restrict__ a,                // [H, 2*F_OUT]
    const void* __restrict__ ba,               // [H]
    void* __restrict__ out,                    // [N, H*F_OUT]
    const void* __restrict__ feat)             // for dtype probe only
{
    const int isbf = detect_bf16((const unsigned int*)feat);

    const int n    = blockIdx.x;
    const int wave = threadIdx.x >> 6;
    const int lane = threadIdx.x & 63;
    const int hh   = blockIdx.y * 4 + wave;

    int nbr_reg = n;                       // lanes 16..63 hold self; self edge last
    if (lane < DEG) nbr_reg = adj[n * DEG + lane];

    const int f0 = lane * 2;
    float adst0, adst1, asrc0, asrc1, bav;
    if (isbf) {
        const unsigned short* a16 = (const unsigned short*)a;
        adst0 = bf2f(a16[hh * 256 + f0]);
        adst1 = bf2f(a16[hh * 256 + f0 + 1]);
        asrc0 = bf2f(a16[hh * 256 + 128 + f0]);
        asrc1 = bf2f(a16[hh * 256 + 128 + f0 + 1]);
        bav   = bf2f(((const unsigned short*)ba)[hh]);
    } else {
        const float* a32 = (const float*)a;
        adst0 = a32[hh * 256 + f0];
        adst1 = a32[hh * 256 + f0 + 1];
        asrc0 = a32[hh * 256 + 128 + f0];
        asrc1 = a32[hh * 256 + 128 + f0 + 1];
        bav   = ((const float*)ba)[hh];
    }

    const __hip_bfloat16* hb = hbuf + (size_t)hh * N_NODES * F_OUT;

    float v0[17], v1[17], red[18];
#pragma unroll
    for (int d = 0; d < 17; ++d) {
        int nb = __shfl(nbr_reg, d, 64);
        unsigned int pk = *(const unsigned int*)&hb[(size_t)nb * F_OUT + f0];
        v0[d] = bf2f((unsigned short)(pk & 0xffffu));
        v1[d] = bf2f((unsigned short)(pk >> 16));
        red[d] = v0[d] * asrc0 + v1[d] * asrc1;   // s_src partials
    }
    red[17] = v0[16] * adst0 + v1[16] * adst1;    // s_dst partial (self row)

#pragma unroll
    for (int off = 1; off < 64; off <<= 1)
#pragma unroll
        for (int r = 0; r < 18; ++r)
            red[r] += __shfl_xor(red[r], off, 64);

    const float sd = red[17] + bav;
    float sc[17], mx = -1e30f;
#pragma unroll
    for (int d = 0; d < 17; ++d) {
        float s = sd + red[d];
        s = s > 0.f ? s : 0.2f * s;               // leaky_relu(0.2)
        sc[d] = s;
        mx = fmaxf(mx, s);
    }
    float ssum = 0.f;
#pragma unroll
    for (int d = 0; d < 17; ++d) { sc[d] = __expf(sc[d] - mx); ssum += sc[d]; }
    const float inv = 1.f / ssum;

    float o0 = 0.f, o1 = 0.f;
#pragma unroll
    for (int d = 0; d < 17; ++d) { o0 += sc[d] * v0[d]; o1 += sc[d] * v1[d]; }
    o0 *= inv; o1 *= inv;

    const size_t oidx = (size_t)n * (NH * F_OUT) + hh * F_OUT + f0;
    if (isbf) {
        __hip_bfloat162 res;
        res.x = __float2bfloat16(o0);
        res.y = __float2bfloat16(o1);
        *(__hip_bfloat162*)&((__hip_bfloat16*)out)[oidx] = res;
    } else {
        float2 res; res.x = o0; res.y = o1;
        *(float2*)&((float*)out)[oidx] = res;
    }
}

// ---------------------------------------------------------------------------
// ws: hbuf bf16 [8][8192][128] = 16 MB exact, in BOTH dtype worlds.
// Input/output dtype is detected at runtime from features' bit patterns
// (R1-R3 NaNs across ws sizes 34.5/18.5/16 MB implicate dtype, not ws).
// ---------------------------------------------------------------------------
extern "C" void kernel_launch(void* const* d_in, const int* in_sizes, int n_in,
                              void* d_out, int out_size, void* d_ws, size_t ws_size,
                              hipStream_t stream)
{
    const void* feat = d_in[0];            // [8192,1024]
    const int*  adj  = (const int*)d_in[1];// [8192,16] i32
    const void* W    = d_in[2];            // [8,1024,128]
    const void* bW   = d_in[3];            // [8,128]
    const void* a    = d_in[4];            // [8,256]
    const void* ba   = d_in[5];            // [8]

    __hip_bfloat16* hbuf = (__hip_bfloat16*)d_ws;   // 16 MB exact

    gat_gemm<<<dim3(64, 8), 256, 0, stream>>>(feat, W, bW, hbuf);
    gat_aggr<<<dim3(8192, 2), 256, 0, stream>>>(hbuf, adj, a, ba, d_out, feat);
}

// Round 5
// 204.857 us; speedup vs baseline: 1.1710x; 1.1710x over previous
//
#include <hip/hip_runtime.h>
#include <hip/hip_bf16.h>

#define N_NODES 8192
#define DEG     16
#define F_IN    1024
#define F_OUT   128
#define NH      8

typedef __bf16 bf16x8 __attribute__((ext_vector_type(8)));
typedef float  f32x4  __attribute__((ext_vector_type(4)));

__device__ __forceinline__ float bf2f(unsigned short u) {
    union { unsigned int i; float f; } v;
    v.i = ((unsigned int)u) << 16;
    return v.f;
}
// fp32 -> bf16 RNE (finite inputs)
__device__ __forceinline__ unsigned short f2bf(float f) {
    union { float f; unsigned int u; } v; v.f = f;
    unsigned int u = v.u + 0x7FFFu + ((v.u >> 16) & 1u);
    return (unsigned short)(u >> 16);
}
// Runtime dtype probe on raw features (validated R4: fp32 world -> 0 hits).
__device__ __forceinline__ int detect_bf16(const unsigned int* __restrict__ w) {
    int hits = 0;
#pragma unroll
    for (int i = 0; i < 64; ++i) {
        unsigned int x = w[i * 131 + 17];
        int e = (x >> 7) & 0xFF;
        hits += (e >= 100 && e <= 140) ? 1 : 0;
    }
    return hits > 32;
}
__device__ __forceinline__ float rd_scalar(const void* p, int idx, int isbf) {
    return isbf ? bf2f(((const unsigned short*)p)[idx]) : ((const float*)p)[idx];
}

// ---------------------------------------------------------------------------
// Kernel 0 (tier A only): convert feat + W to bf16 once. 8 elems/thread.
// ---------------------------------------------------------------------------
__global__ __launch_bounds__(256) void conv_inputs(
    const void* __restrict__ feat, const void* __restrict__ W,
    unsigned short* __restrict__ featb, unsigned short* __restrict__ Wb)
{
    const int isbf = detect_bf16((const unsigned int*)feat);
    const size_t FEAT_E = (size_t)N_NODES * F_IN;           // 8388608
    size_t i8 = ((size_t)blockIdx.x * 256 + threadIdx.x) * 8;
    unsigned short* dst;
    const void* src;
    size_t off;
    if (i8 < FEAT_E) { dst = featb + i8; src = feat; off = i8; }
    else             { off = i8 - FEAT_E; dst = Wb + off; src = W; }
    if (isbf) {
        *(uint4*)dst = *((const uint4*)src + off / 8);
    } else {
        const float* s = (const float*)src + off;
        float4 u0 = *(const float4*)s;
        float4 u1 = *(const float4*)(s + 4);
        unsigned short t[8] = { f2bf(u0.x), f2bf(u0.y), f2bf(u0.z), f2bf(u0.w),
                                f2bf(u1.x), f2bf(u1.y), f2bf(u1.z), f2bf(u1.w) };
        *(uint4*)dst = *(const uint4*)t;
    }
}

// ---------------------------------------------------------------------------
// Kernel 1: per-head GEMM h = feat @ W[h] + bW[h]; 128x128 tile, BK=64,
// mfma_f32_16x16x32_bf16, fp32 acc, bf16 store. Optional fused score epilogue:
// sdst[h][n] = h·a_dst + ba, ssrc[h][n] = h·a_src (fp32, from un-rounded acc).
// staged=1 -> stage_feat/stage_W are pre-converted bf16.
// ---------------------------------------------------------------------------
__global__ __launch_bounds__(256) void gat_gemm(
    const void* __restrict__ stage_feat, const void* __restrict__ stage_W,
    const void* __restrict__ raw_feat,
    const void* __restrict__ bW, const void* __restrict__ a,
    const void* __restrict__ ba,
    __hip_bfloat16* __restrict__ hbuf,
    float* __restrict__ sdst, float* __restrict__ ssrc,
    int staged, int do_scores)
{
    const int rawbf = detect_bf16((const unsigned int*)raw_feat);
    const int sbf   = staged | rawbf;

    const int h   = blockIdx.y;
    const int n0  = blockIdx.x * 128;
    const int tid = threadIdx.x;

    __shared__ __align__(16) unsigned short As[128][72];  // [node][k]
    __shared__ __align__(16) unsigned short Bs[128][72];  // [o][k]

    const int lane = tid & 63;
    const int wave = tid >> 6;
    const int quad = lane >> 4;
    const int l16  = lane & 15;

    f32x4 acc[2][8];
#pragma unroll
    for (int i = 0; i < 2; ++i)
#pragma unroll
        for (int j = 0; j < 8; ++j) acc[i][j] = (f32x4)0.f;

    for (int k0 = 0; k0 < F_IN; k0 += 64) {
        if (sbf) {
            const unsigned short* fbase = (const unsigned short*)stage_feat + (size_t)n0 * F_IN;
            const unsigned short* wsrc  = (const unsigned short*)stage_W +
                                          (size_t)h * F_IN * F_OUT + (size_t)k0 * F_OUT;
#pragma unroll
            for (int t = 0; t < 4; ++t) {
                int c = t * 256 + tid, row = c >> 3, kc = c & 7;
                *(uint4*)&As[row][kc * 8] =
                    *(const uint4*)&fbase[row * F_IN + k0 + kc * 8];
            }
#pragma unroll
            for (int t = 0; t < 2; ++t) {
                int c = t * 256 + tid;
                int kr2 = c >> 4, m = c & 15, oc = m * 8;
                uint4 w0 = *(const uint4*)&wsrc[(2 * kr2    ) * F_OUT + oc];
                uint4 w1 = *(const uint4*)&wsrc[(2 * kr2 + 1) * F_OUT + oc];
                const unsigned short* p0 = (const unsigned short*)&w0;
                const unsigned short* p1 = (const unsigned short*)&w1;
#pragma unroll
                for (int j = 0; j < 8; ++j) {
                    int i = (j + m) & 7;
                    unsigned int val = (unsigned int)p0[i] | ((unsigned int)p1[i] << 16);
                    *(unsigned int*)&Bs[oc + i][2 * kr2] = val;
                }
            }
        } else {
            const float* fbase = (const float*)stage_feat + (size_t)n0 * F_IN;
            const float* wsrc  = (const float*)stage_W +
                                 (size_t)h * F_IN * F_OUT + (size_t)k0 * F_OUT;
#pragma unroll
            for (int t = 0; t < 4; ++t) {
                int c = t * 256 + tid, row = c >> 3, kc = c & 7;
                const float* src = &fbase[row * F_IN + k0 + kc * 8];
                float4 u0 = *(const float4*)src;
                float4 u1 = *(const float4*)(src + 4);
                unsigned short s[8] = { f2bf(u0.x), f2bf(u0.y), f2bf(u0.z), f2bf(u0.w),
                                        f2bf(u1.x), f2bf(u1.y), f2bf(u1.z), f2bf(u1.w) };
                *(uint4*)&As[row][kc * 8] = *(const uint4*)s;
            }
#pragma unroll
            for (int t = 0; t < 2; ++t) {
                int c = t * 256 + tid;
                int kr2 = c >> 4, m = c & 15, oc = m * 8;
                const float* r0 = &wsrc[(2 * kr2    ) * F_OUT + oc];
                const float* r1 = &wsrc[(2 * kr2 + 1) * F_OUT + oc];
                float4 e0 = *(const float4*)r0, e1 = *(const float4*)(r0 + 4);
                float4 o0 = *(const float4*)r1, o1 = *(const float4*)(r1 + 4);
                unsigned short p0[8] = { f2bf(e0.x), f2bf(e0.y), f2bf(e0.z), f2bf(e0.w),
                                         f2bf(e1.x), f2bf(e1.y), f2bf(e1.z), f2bf(e1.w) };
                unsigned short p1[8] = { f2bf(o0.x), f2bf(o0.y), f2bf(o0.z), f2bf(o0.w),
                                         f2bf(o1.x), f2bf(o1.y), f2bf(o1.z), f2bf(o1.w) };
#pragma unroll
                for (int j = 0; j < 8; ++j) {
                    int i = (j + m) & 7;
                    unsigned int val = (unsigned int)p0[i] | ((unsigned int)p1[i] << 16);
                    *(unsigned int*)&Bs[oc + i][2 * kr2] = val;
                }
            }
        }
        __syncthreads();

#pragma unroll
        for (int ks = 0; ks < 2; ++ks) {
            const int kk = ks * 32 + quad * 8;
            bf16x8 af[2], bfr[8];
#pragma unroll
            for (int rt = 0; rt < 2; ++rt)
                af[rt] = *(const bf16x8*)&As[wave * 32 + rt * 16 + l16][kk];
#pragma unroll
            for (int ct = 0; ct < 8; ++ct)
                bfr[ct] = *(const bf16x8*)&Bs[ct * 16 + l16][kk];
#pragma unroll
            for (int rt = 0; rt < 2; ++rt)
#pragma unroll
                for (int ct = 0; ct < 8; ++ct)
                    acc[rt][ct] = __builtin_amdgcn_mfma_f32_16x16x32_bf16(
                        af[rt], bfr[ct], acc[rt][ct], 0, 0, 0);
        }
        __syncthreads();
    }

    // h-tile store (D: col = lane&15, row = quad*4 + reg — m89/m91)
#pragma unroll
    for (int ct = 0; ct < 8; ++ct) {
        const int col = ct * 16 + l16;
        const float bwv = rd_scalar(bW, h * F_OUT + col, rawbf);
#pragma unroll
        for (int rt = 0; rt < 2; ++rt) {
            const int nrow = n0 + wave * 32 + rt * 16 + quad * 4;
            __hip_bfloat16* dst = hbuf + ((size_t)h * N_NODES + nrow) * F_OUT + col;
#pragma unroll
            for (int r = 0; r < 4; ++r)
                dst[(size_t)r * F_OUT] = __float2bfloat16(acc[rt][ct][r] + bwv);
        }
    }

    // fused scores: pd/ps = row dot a_dst/a_src; reduce over l16 (lane bits 0-3)
    if (do_scores) {
        float adst[8], asrc[8];
#pragma unroll
        for (int ct = 0; ct < 8; ++ct) {
            const int col = ct * 16 + l16;
            adst[ct] = rd_scalar(a, h * 256 + col, rawbf);
            asrc[ct] = rd_scalar(a, h * 256 + 128 + col, rawbf);
        }
        float pd[2][4] = {}, ps[2][4] = {};
#pragma unroll
        for (int rt = 0; rt < 2; ++rt)
#pragma unroll
            for (int ct = 0; ct < 8; ++ct)
#pragma unroll
                for (int r = 0; r < 4; ++r) {
                    pd[rt][r] += acc[rt][ct][r] * adst[ct];
                    ps[rt][r] += acc[rt][ct][r] * asrc[ct];
                }
#pragma unroll
        for (int off = 1; off < 16; off <<= 1)
#pragma unroll
            for (int rt = 0; rt < 2; ++rt)
#pragma unroll
                for (int r = 0; r < 4; ++r) {
                    pd[rt][r] += __shfl_xor(pd[rt][r], off, 64);
                    ps[rt][r] += __shfl_xor(ps[rt][r], off, 64);
                }
        if (l16 == 0) {
            const float bav = rd_scalar(ba, h, rawbf);
#pragma unroll
            for (int rt = 0; rt < 2; ++rt) {
                const int base = n0 + wave * 32 + rt * 16 + quad * 4;
                float4 vd = { pd[rt][0] + bav, pd[rt][1] + bav,
                              pd[rt][2] + bav, pd[rt][3] + bav };
                float4 vs = { ps[rt][0], ps[rt][1], ps[rt][2], ps[rt][3] };
                *(float4*)&sdst[h * N_NODES + base] = vd;
                *(float4*)&ssrc[h * N_NODES + base] = vs;
            }
        }
    }
}

// ---------------------------------------------------------------------------
// Kernel 2 (tiers A/B): block per node, all 8 heads. Softmax from precomputed
// scores; uint2 (4xbf16) gather loads; 4 features/thread.
// ---------------------------------------------------------------------------
__global__ __launch_bounds__(256) void gat_aggr2(
    const __hip_bfloat16* __restrict__ hbuf,
    const int* __restrict__ adj,
    const float* __restrict__ sdst, const float* __restrict__ ssrc,
    const void* __restrict__ raw_feat, void* __restrict__ out)
{
    const int isbf = detect_bf16((const unsigned int*)raw_feat);
    const int n = blockIdx.x, t = threadIdx.x;

    __shared__ int   nbr[17];
    __shared__ float scs[NH][17];
    __shared__ float al[NH][17];

    if (t < 16)       nbr[t] = adj[n * DEG + t];
    else if (t == 16) nbr[16] = n;                    // self edge last
    __syncthreads();

    if (t < NH * 17) {
        const int hh = t / 17, d = t % 17;
        float s = sdst[hh * N_NODES + n] + ssrc[hh * N_NODES + nbr[d]];
        scs[hh][d] = s > 0.f ? s : 0.2f * s;          // leaky_relu(0.2)
    }
    __syncthreads();

    if (t < NH) {
        float m = -1e30f;
#pragma unroll
        for (int d = 0; d < 17; ++d) m = fmaxf(m, scs[t][d]);
        float e[17], ssum = 0.f;
#pragma unroll
        for (int d = 0; d < 17; ++d) { e[d] = __expf(scs[t][d] - m); ssum += e[d]; }
        const float inv = 1.f / ssum;
#pragma unroll
        for (int d = 0; d < 17; ++d) al[t][d] = e[d] * inv;
    }
    __syncthreads();

    const int hh = t >> 5;                 // head
    const int fc = (t & 31) * 4;           // feature chunk
    const unsigned short* hb = (const unsigned short*)hbuf + (size_t)hh * N_NODES * F_OUT;

    float a0 = 0.f, a1 = 0.f, a2 = 0.f, a3 = 0.f;
#pragma unroll
    for (int d = 0; d < 17; ++d) {
        const int nb = nbr[d];
        const float av = al[hh][d];
        uint2 pk = *(const uint2*)&hb[(size_t)nb * F_OUT + fc];
        a0 += av * bf2f((unsigned short)(pk.x & 0xffffu));
        a1 += av * bf2f((unsigned short)(pk.x >> 16));
        a2 += av * bf2f((unsigned short)(pk.y & 0xffffu));
        a3 += av * bf2f((unsigned short)(pk.y >> 16));
    }

    const size_t oidx = (size_t)n * (NH * F_OUT) + hh * F_OUT + fc;
    if (isbf) {
        uint2 res;
        res.x = (unsigned int)f2bf(a0) | ((unsigned int)f2bf(a1) << 16);
        res.y = (unsigned int)f2bf(a2) | ((unsigned int)f2bf(a3) << 16);
        *(uint2*)&((unsigned short*)out)[oidx] = res;
    } else {
        float4 res = { a0, a1, a2, a3 };
        *(float4*)&((float*)out)[oidx] = res;
    }
}

// ---------------------------------------------------------------------------
// Kernel 2-fallback (tier C, exact R4 shape): butterfly score recompute.
// ---------------------------------------------------------------------------
__global__ __launch_bounds__(256) void gat_aggr_r4(
    const __hip_bfloat16* __restrict__ hbuf, const int* __restrict__ adj,
    const void* __restrict__ a, const void* __restrict__ ba,
    void* __restrict__ out, const void* __restrict__ feat)
{
    const int isbf = detect_bf16((const unsigned int*)feat);
    const int n    = blockIdx.x;
    const int wave = threadIdx.x >> 6;
    const int lane = threadIdx.x & 63;
    const int hh   = blockIdx.y * 4 + wave;

    int nbr_reg = n;
    if (lane < DEG) nbr_reg = adj[n * DEG + lane];

    const int f0 = lane * 2;
    const float adst0 = rd_scalar(a, hh * 256 + f0, isbf);
    const float adst1 = rd_scalar(a, hh * 256 + f0 + 1, isbf);
    const float asrc0 = rd_scalar(a, hh * 256 + 128 + f0, isbf);
    const float asrc1 = rd_scalar(a, hh * 256 + 128 + f0 + 1, isbf);
    const float bav   = rd_scalar(ba, hh, isbf);

    const __hip_bfloat16* hb = hbuf + (size_t)hh * N_NODES * F_OUT;

    float v0[17], v1[17], red[18];
#pragma unroll
    for (int d = 0; d < 17; ++d) {
        int nb = __shfl(nbr_reg, d, 64);
        unsigned int pk = *(const unsigned int*)&hb[(size_t)nb * F_OUT + f0];
        v0[d] = bf2f((unsigned short)(pk & 0xffffu));
        v1[d] = bf2f((unsigned short)(pk >> 16));
        red[d] = v0[d] * asrc0 + v1[d] * asrc1;
    }
    red[17] = v0[16] * adst0 + v1[16] * adst1;
#pragma unroll
    for (int off = 1; off < 64; off <<= 1)
#pragma unroll
        for (int r = 0; r < 18; ++r)
            red[r] += __shfl_xor(red[r], off, 64);

    const float sd = red[17] + bav;
    float sc[17], mx = -1e30f;
#pragma unroll
    for (int d = 0; d < 17; ++d) {
        float s = sd + red[d];
        s = s > 0.f ? s : 0.2f * s;
        sc[d] = s; mx = fmaxf(mx, s);
    }
    float ssum = 0.f;
#pragma unroll
    for (int d = 0; d < 17; ++d) { sc[d] = __expf(sc[d] - mx); ssum += sc[d]; }
    const float inv = 1.f / ssum;
    float o0 = 0.f, o1 = 0.f;
#pragma unroll
    for (int d = 0; d < 17; ++d) { o0 += sc[d] * v0[d]; o1 += sc[d] * v1[d]; }
    o0 *= inv; o1 *= inv;

    const size_t oidx = (size_t)n * (NH * F_OUT) + hh * F_OUT + f0;
    if (isbf) {
        unsigned int res = (unsigned int)f2bf(o0) | ((unsigned int)f2bf(o1) << 16);
        *(unsigned int*)&((unsigned short*)out)[oidx] = res;
    } else {
        float2 res; res.x = o0; res.y = o1;
        *(float2*)&((float*)out)[oidx] = res;
    }
}

// ---------------------------------------------------------------------------
// ws layout (tier A, 34.5 MiB): hbuf 16M | sdst 256K | ssrc 256K | featb 16M | Wb 2M
// tier B (16.5 MiB): hbuf | sdst | ssrc.  tier C (<16.5 MiB): hbuf only.
// ---------------------------------------------------------------------------
extern "C" void kernel_launch(void* const* d_in, const int* in_sizes, int n_in,
                              void* d_out, int out_size, void* d_ws, size_t ws_size,
                              hipStream_t stream)
{
    const void* feat = d_in[0];
    const int*  adj  = (const int*)d_in[1];
    const void* W    = d_in[2];
    const void* bW   = d_in[3];
    const void* a    = d_in[4];
    const void* ba   = d_in[5];

    char* ws = (char*)d_ws;
    __hip_bfloat16* hbuf = (__hip_bfloat16*)ws;
    const size_t HB = (size_t)NH * N_NODES * F_OUT * 2;       // 16 MiB
    const size_t SC = (size_t)NH * N_NODES * 4;               // 256 KiB
    float* sdst = (float*)(ws + HB);
    float* ssrc = (float*)(ws + HB + SC);
    unsigned short* featb = (unsigned short*)(ws + HB + 2 * SC);
    unsigned short* Wb    = featb + (size_t)N_NODES * F_IN;

    const size_t needB = HB + 2 * SC;                                        // 16.5 MiB
    const size_t needA = needB + ((size_t)N_NODES * F_IN + (size_t)NH * F_IN * F_OUT) * 2; // 34.5 MiB

    if (ws_size >= needA) {
        conv_inputs<<<4608, 256, 0, stream>>>(feat, W, featb, Wb);
        gat_gemm<<<dim3(64, 8), 256, 0, stream>>>(featb, Wb, feat, bW, a, ba,
                                                  hbuf, sdst, ssrc, 1, 1);
        gat_aggr2<<<8192, 256, 0, stream>>>(hbuf, adj, sdst, ssrc, feat, d_out);
    } else if (ws_size >= needB) {
        gat_gemm<<<dim3(64, 8), 256, 0, stream>>>(feat, W, feat, bW, a, ba,
                                                  hbuf, sdst, ssrc, 0, 1);
        gat_aggr2<<<8192, 256, 0, stream>>>(hbuf, adj, sdst, ssrc, feat, d_out);
    } else {
        gat_gemm<<<dim3(64, 8), 256, 0, stream>>>(feat, W, feat, bW, a, ba,
                                                  hbuf, (float*)ws, (float*)ws, 0, 0);
        gat_aggr_r4<<<dim3(8192, 2), 256, 0, stream>>>(hbuf, adj, a, ba, d_out, feat);
    }
}

// Round 6
// 171.378 us; speedup vs baseline: 1.3997x; 1.1954x over previous
//
#include <hip/hip_runtime.h>
#include <hip/hip_bf16.h>

#define N_NODES 8192
#define DEG     16
#define F_IN    1024
#define F_OUT   128
#define NH      8

typedef __bf16 bf16x8 __attribute__((ext_vector_type(8)));
typedef float  f32x4  __attribute__((ext_vector_type(4)));

__device__ __forceinline__ float bf2f(unsigned short u) {
    union { unsigned int i; float f; } v;
    v.i = ((unsigned int)u) << 16;
    return v.f;
}
__device__ __forceinline__ unsigned short f2bf(float f) {
    union { float f; unsigned int u; } v; v.f = f;
    unsigned int u = v.u + 0x7FFFu + ((v.u >> 16) & 1u);
    return (unsigned short)(u >> 16);
}
// Runtime dtype probe (validated R4/R5: fp32 world). Wave-uniform.
__device__ __forceinline__ int detect_bf16(const unsigned int* __restrict__ w) {
    int hits = 0;
#pragma unroll
    for (int i = 0; i < 64; ++i) {
        unsigned int x = w[i * 131 + 17];
        int e = (x >> 7) & 0xFF;
        hits += (e >= 100 && e <= 140) ? 1 : 0;
    }
    return hits > 32;
}
__device__ __forceinline__ float rd_scalar(const void* p, int idx, int isbf) {
    return isbf ? bf2f(((const unsigned short*)p)[idx]) : ((const float*)p)[idx];
}
// async global->LDS, 16B per lane; LDS dest = wave-uniform base + lane*16
__device__ __forceinline__ void gload16(const void* g, void* l) {
    __builtin_amdgcn_global_load_lds(
        (const __attribute__((address_space(1))) void*)g,
        (__attribute__((address_space(3))) void*)l, 16, 0, 0);
}

// ---------------------------------------------------------------------------
// conv_feat: features -> bf16 (straight convert/copy). 8 elems/thread.
// ---------------------------------------------------------------------------
__global__ __launch_bounds__(256) void conv_feat(
    const void* __restrict__ feat, unsigned short* __restrict__ featb)
{
    const int isbf = detect_bf16((const unsigned int*)feat);
    size_t i8 = ((size_t)blockIdx.x * 256 + threadIdx.x) * 8;
    if (isbf) {
        *(uint4*)(featb + i8) = ((const uint4*)feat)[i8 / 8];
    } else {
        const float* s = (const float*)feat + i8;
        float4 u0 = *(const float4*)s;
        float4 u1 = *(const float4*)(s + 4);
        unsigned short t[8] = { f2bf(u0.x), f2bf(u0.y), f2bf(u0.z), f2bf(u0.w),
                                f2bf(u1.x), f2bf(u1.y), f2bf(u1.z), f2bf(u1.w) };
        *(uint4*)(featb + i8) = *(const uint4*)t;
    }
}

// ---------------------------------------------------------------------------
// transp_W: W[h][k][o] -> Wt[h][o][k] bf16, 64x64 LDS tile (float tile: +65
// stride -> conflict-free col reads). grid = 8 heads x 16 ktiles x 2 otiles.
// ---------------------------------------------------------------------------
__global__ __launch_bounds__(256) void transp_W(
    const void* __restrict__ W, unsigned short* __restrict__ Wt,
    const void* __restrict__ raw_feat)
{
    const int isbf = detect_bf16((const unsigned int*)raw_feat);
    __shared__ float tile[64][65];
    const int h  = blockIdx.x >> 5;
    const int kt = (blockIdx.x >> 1) & 15;
    const int ot = blockIdx.x & 1;
    const int t  = threadIdx.x;
#pragma unroll
    for (int i = 0; i < 16; ++i) {
        int id = i * 256 + t, r = id >> 6, c = id & 63;
        tile[r][c] = rd_scalar(W, ((h * 1024 + kt * 64 + r) * 128) + ot * 64 + c, isbf);
    }
    __syncthreads();
#pragma unroll
    for (int i = 0; i < 16; ++i) {
        int id = i * 256 + t, oc = id >> 6, kc = id & 63;
        Wt[(size_t)(h * 128 + ot * 64 + oc) * 1024 + kt * 64 + kc] = f2bf(tile[kc][oc]);
    }
}

// ---------------------------------------------------------------------------
// gat_gemm2: h = feat @ W[h] + bW[h], 128x128 tile, BK=64, global_load_lds
// staging (no ds_write!), XOR-swizzled chunks -> 2-way-max bank access.
// Fused score epilogue (sdst = h.a_dst + ba, ssrc = h.a_src, fp32).
// ---------------------------------------------------------------------------
__global__ __launch_bounds__(256) void gat_gemm2(
    const unsigned short* __restrict__ featb,  // [N, F_IN] bf16
    const unsigned short* __restrict__ Wt,     // [H, F_OUT, F_IN] bf16
    const void* __restrict__ raw_feat,
    const void* __restrict__ bW, const void* __restrict__ a,
    const void* __restrict__ ba,
    __hip_bfloat16* __restrict__ hbuf,
    float* __restrict__ sdst, float* __restrict__ ssrc)
{
    const int rawbf = detect_bf16((const unsigned int*)raw_feat);

    const int h   = blockIdx.y;
    const int n0  = blockIdx.x * 128;
    const int tid = threadIdx.x;

    // unpadded [row][8 chunks of 8 bf16]; swizzle handles banks
    __shared__ __align__(16) unsigned short As[128 * 64];
    __shared__ __align__(16) unsigned short Bs[128 * 64];

    const int lane = tid & 63;
    const int wave = tid >> 6;
    const int quad = lane >> 4;
    const int l16  = lane & 15;
    const int sw   = l16 & 7;        // fragment-read swizzle key (= row&7)

    f32x4 acc[2][8];
#pragma unroll
    for (int i = 0; i < 2; ++i)
#pragma unroll
        for (int j = 0; j < 8; ++j) acc[i][j] = (f32x4)0.f;

    const unsigned short* wbase = Wt + (size_t)h * F_OUT * F_IN;

    for (int k0 = 0; k0 < F_IN; k0 += 64) {
        // stage A (128 nodes x 64k) and B (128 o x 64k): 4+4 async 16B/lane
#pragma unroll
        for (int t = 0; t < 4; ++t) {
            const int r0  = t * 32 + wave * 8;           // wave-uniform
            const int row = r0 + (lane >> 3);
            const int gc  = (lane & 7) ^ (row & 7);      // XOR swizzle
            gload16(&featb[(size_t)(n0 + row) * F_IN + k0 + gc * 8], &As[r0 * 64]);
            gload16(&wbase[(size_t)row * F_IN + k0 + gc * 8], &Bs[r0 * 64]);
        }
        __syncthreads();   // drains vmcnt -> LDS valid

#pragma unroll
        for (int ks = 0; ks < 2; ++ks) {
            const int kc = ks * 4 + quad;                // chunk index
            const int cs = (kc ^ sw) * 8;                // swizzled column
            bf16x8 af[2], bfr[8];
#pragma unroll
            for (int rt = 0; rt < 2; ++rt)
                af[rt] = *(const bf16x8*)&As[(wave * 32 + rt * 16 + l16) * 64 + cs];
#pragma unroll
            for (int ct = 0; ct < 8; ++ct)
                bfr[ct] = *(const bf16x8*)&Bs[(ct * 16 + l16) * 64 + cs];
#pragma unroll
            for (int rt = 0; rt < 2; ++rt)
#pragma unroll
                for (int ct = 0; ct < 8; ++ct)
                    acc[rt][ct] = __builtin_amdgcn_mfma_f32_16x16x32_bf16(
                        af[rt], bfr[ct], acc[rt][ct], 0, 0, 0);
        }
        __syncthreads();
    }

    // h-tile store (D: col = lane&15, row = quad*4 + reg — m89/m91)
#pragma unroll
    for (int ct = 0; ct < 8; ++ct) {
        const int col = ct * 16 + l16;
        const float bwv = rd_scalar(bW, h * F_OUT + col, rawbf);
#pragma unroll
        for (int rt = 0; rt < 2; ++rt) {
            const int nrow = n0 + wave * 32 + rt * 16 + quad * 4;
            __hip_bfloat16* dst = hbuf + ((size_t)h * N_NODES + nrow) * F_OUT + col;
#pragma unroll
            for (int r = 0; r < 4; ++r)
                dst[(size_t)r * F_OUT] = __float2bfloat16(acc[rt][ct][r] + bwv);
        }
    }

    // fused scores: reduce row dot a_dst/a_src over l16
    float adst[8], asrc[8];
#pragma unroll
    for (int ct = 0; ct < 8; ++ct) {
        const int col = ct * 16 + l16;
        adst[ct] = rd_scalar(a, h * 256 + col, rawbf);
        asrc[ct] = rd_scalar(a, h * 256 + 128 + col, rawbf);
    }
    float pd[2][4] = {}, ps[2][4] = {};
#pragma unroll
    for (int rt = 0; rt < 2; ++rt)
#pragma unroll
        for (int ct = 0; ct < 8; ++ct)
#pragma unroll
            for (int r = 0; r < 4; ++r) {
                pd[rt][r] += acc[rt][ct][r] * adst[ct];
                ps[rt][r] += acc[rt][ct][r] * asrc[ct];
            }
#pragma unroll
    for (int off = 1; off < 16; off <<= 1)
#pragma unroll
        for (int rt = 0; rt < 2; ++rt)
#pragma unroll
            for (int r = 0; r < 4; ++r) {
                pd[rt][r] += __shfl_xor(pd[rt][r], off, 64);
                ps[rt][r] += __shfl_xor(ps[rt][r], off, 64);
            }
    if (l16 == 0) {
        const float bav = rd_scalar(ba, h, rawbf);
#pragma unroll
        for (int rt = 0; rt < 2; ++rt) {
            const int base = n0 + wave * 32 + rt * 16 + quad * 4;
            float4 vd = { pd[rt][0] + bav, pd[rt][1] + bav,
                          pd[rt][2] + bav, pd[rt][3] + bav };
            float4 vs = { ps[rt][0], ps[rt][1], ps[rt][2], ps[rt][3] };
            *(float4*)&sdst[h * N_NODES + base] = vd;
            *(float4*)&ssrc[h * N_NODES + base] = vs;
        }
    }
}

// ---------------------------------------------------------------------------
// gat_aggr3: fully wave-local. One wave = (node, 2 heads); 32-lane half per
// head. Softmax via shfl_xor within half; alpha broadcast via shfl.
// Zero LDS, zero barriers, no idle phases.
// ---------------------------------------------------------------------------
__global__ __launch_bounds__(256) void gat_aggr3(
    const unsigned short* __restrict__ hbuf,   // [H, N, F_OUT] bf16
    const int* __restrict__ adj,
    const float* __restrict__ sdst, const float* __restrict__ ssrc,
    const void* __restrict__ raw_feat, void* __restrict__ out)
{
    const int isbf = detect_bf16((const unsigned int*)raw_feat);
    const int n    = blockIdx.x;
    const int wave = threadIdx.x >> 6;
    const int lane = threadIdx.x & 63;
    const int half = lane >> 5;
    const int l32  = lane & 31;
    const int hh   = wave * 2 + half;

    int nbr = n;                              // self edge is slot 16
    if (l32 < DEG) nbr = adj[n * DEG + l32];

    float s = -1e30f;
    if (l32 < 17) {
        float sv = sdst[hh * N_NODES + n] + ssrc[hh * N_NODES + nbr];
        s = sv > 0.f ? sv : 0.2f * sv;        // leaky_relu(0.2)
    }
    float m = s;
#pragma unroll
    for (int off = 1; off < 32; off <<= 1)    // xor stays within 32-half
        m = fmaxf(m, __shfl_xor(m, off, 64));
    float ev = (l32 < 17) ? __expf(s - m) : 0.f;
    float sum = ev;
#pragma unroll
    for (int off = 1; off < 32; off <<= 1)
        sum += __shfl_xor(sum, off, 64);
    ev *= (1.f / sum);                        // normalized alpha (lanes d<17)

    const unsigned short* hb = hbuf + (size_t)hh * N_NODES * F_OUT;
    const int fc    = l32 * 4;
    const int sbase = half << 5;
    float a0 = 0.f, a1 = 0.f, a2 = 0.f, a3 = 0.f;
#pragma unroll
    for (int d = 0; d < 17; ++d) {
        const int   nb = __shfl(nbr, sbase + d, 64);
        const float av = __shfl(ev,  sbase + d, 64);
        uint2 pk = *(const uint2*)&hb[(size_t)nb * F_OUT + fc];
        a0 += av * bf2f((unsigned short)(pk.x & 0xffffu));
        a1 += av * bf2f((unsigned short)(pk.x >> 16));
        a2 += av * bf2f((unsigned short)(pk.y & 0xffffu));
        a3 += av * bf2f((unsigned short)(pk.y >> 16));
    }

    const size_t oidx = (size_t)n * (NH * F_OUT) + hh * F_OUT + fc;
    if (isbf) {
        uint2 res;
        res.x = (unsigned int)f2bf(a0) | ((unsigned int)f2bf(a1) << 16);
        res.y = (unsigned int)f2bf(a2) | ((unsigned int)f2bf(a3) << 16);
        *(uint2*)&((unsigned short*)out)[oidx] = res;
    } else {
        float4 res = { a0, a1, a2, a3 };
        *(float4*)&((float*)out)[oidx] = res;
    }
}

// ---------------------------------------------------------------------------
// Fallback tier (R4-proven pair) — only if ws < 34.5 MiB (never seen; R5
// dispatch timing proves tier A ran, i.e. ws >= 34.5 MiB).
// ---------------------------------------------------------------------------
__global__ __launch_bounds__(256) void gat_gemm_fb(
    const void* __restrict__ feat, const void* __restrict__ W,
    const void* __restrict__ bW, __hip_bfloat16* __restrict__ hbuf)
{
    const int isbf = detect_bf16((const unsigned int*)feat);
    const int h = blockIdx.y, n0 = blockIdx.x * 128, tid = threadIdx.x;
    __shared__ __align__(16) unsigned short As[128][72];
    __shared__ __align__(16) unsigned short Bs[128][72];
    const int lane = tid & 63, wave = tid >> 6, quad = lane >> 4, l16 = lane & 15;
    f32x4 acc[2][8];
#pragma unroll
    for (int i = 0; i < 2; ++i)
#pragma unroll
        for (int j = 0; j < 8; ++j) acc[i][j] = (f32x4)0.f;
    for (int k0 = 0; k0 < F_IN; k0 += 64) {
        if (isbf) {
            const unsigned short* fbase = (const unsigned short*)feat + (size_t)n0 * F_IN;
            const unsigned short* wsrc  = (const unsigned short*)W +
                                          (size_t)h * F_IN * F_OUT + (size_t)k0 * F_OUT;
#pragma unroll
            for (int t = 0; t < 4; ++t) {
                int c = t * 256 + tid, row = c >> 3, kc = c & 7;
                *(uint4*)&As[row][kc * 8] = *(const uint4*)&fbase[row * F_IN + k0 + kc * 8];
            }
#pragma unroll
            for (int t = 0; t < 2; ++t) {
                int c = t * 256 + tid, kr2 = c >> 4, mm = c & 15, oc = mm * 8;
                uint4 w0 = *(const uint4*)&wsrc[(2 * kr2) * F_OUT + oc];
                uint4 w1 = *(const uint4*)&wsrc[(2 * kr2 + 1) * F_OUT + oc];
                const unsigned short* p0 = (const unsigned short*)&w0;
                const unsigned short* p1 = (const unsigned short*)&w1;
#pragma unroll
                for (int j = 0; j < 8; ++j) {
                    int i = (j + mm) & 7;
                    *(unsigned int*)&Bs[oc + i][2 * kr2] =
                        (unsigned int)p0[i] | ((unsigned int)p1[i] << 16);
                }
            }
        } else {
            const float* fbase = (const float*)feat + (size_t)n0 * F_IN;
            const float* wsrc  = (const float*)W +
                                 (size_t)h * F_IN * F_OUT + (size_t)k0 * F_OUT;
#pragma unroll
            for (int t = 0; t < 4; ++t) {
                int c = t * 256 + tid, row = c >> 3, kc = c & 7;
                const float* src = &fbase[row * F_IN + k0 + kc * 8];
                float4 u0 = *(const float4*)src, u1 = *(const float4*)(src + 4);
                unsigned short sh[8] = { f2bf(u0.x), f2bf(u0.y), f2bf(u0.z), f2bf(u0.w),
                                         f2bf(u1.x), f2bf(u1.y), f2bf(u1.z), f2bf(u1.w) };
                *(uint4*)&As[row][kc * 8] = *(const uint4*)sh;
            }
#pragma unroll
            for (int t = 0; t < 2; ++t) {
                int c = t * 256 + tid, kr2 = c >> 4, mm = c & 15, oc = mm * 8;
                const float* r0 = &wsrc[(2 * kr2) * F_OUT + oc];
                const float* r1 = &wsrc[(2 * kr2 + 1) * F_OUT + oc];
                float4 e0 = *(const float4*)r0, e1 = *(const float4*)(r0 + 4);
                float4 o0 = *(const float4*)r1, o1 = *(const float4*)(r1 + 4);
                unsigned short p0[8] = { f2bf(e0.x), f2bf(e0.y), f2bf(e0.z), f2bf(e0.w),
                                         f2bf(e1.x), f2bf(e1.y), f2bf(e1.z), f2bf(e1.w) };
                unsigned short p1[8] = { f2bf(o0.x), f2bf(o0.y), f2bf(o0.z), f2bf(o0.w),
                                         f2bf(o1.x), f2bf(o1.y), f2bf(o1.z), f2bf(o1.w) };
#pragma unroll
                for (int j = 0; j < 8; ++j) {
                    int i = (j + mm) & 7;
                    *(unsigned int*)&Bs[oc + i][2 * kr2] =
                        (unsigned int)p0[i] | ((unsigned int)p1[i] << 16);
                }
            }
        }
        __syncthreads();
#pragma unroll
        for (int ks = 0; ks < 2; ++ks) {
            const int kk = ks * 32 + quad * 8;
            bf16x8 af[2], bfr[8];
#pragma unroll
            for (int rt = 0; rt < 2; ++rt)
                af[rt] = *(const bf16x8*)&As[wave * 32 + rt * 16 + l16][kk];
#pragma unroll
            for (int ct = 0; ct < 8; ++ct)
                bfr[ct] = *(const bf16x8*)&Bs[ct * 16 + l16][kk];
#pragma unroll
            for (int rt = 0; rt < 2; ++rt)
#pragma unroll
                for (int ct = 0; ct < 8; ++ct)
                    acc[rt][ct] = __builtin_amdgcn_mfma_f32_16x16x32_bf16(
                        af[rt], bfr[ct], acc[rt][ct], 0, 0, 0);
        }
        __syncthreads();
    }
#pragma unroll
    for (int ct = 0; ct < 8; ++ct) {
        const int col = ct * 16 + l16;
        const float bwv = rd_scalar(bW, h * F_OUT + col, isbf);
#pragma unroll
        for (int rt = 0; rt < 2; ++rt) {
            const int nrow = n0 + wave * 32 + rt * 16 + quad * 4;
            __hip_bfloat16* dst = hbuf + ((size_t)h * N_NODES + nrow) * F_OUT + col;
#pragma unroll
            for (int r = 0; r < 4; ++r)
                dst[(size_t)r * F_OUT] = __float2bfloat16(acc[rt][ct][r] + bwv);
        }
    }
}

__global__ __launch_bounds__(256) void gat_aggr_fb(
    const __hip_bfloat16* __restrict__ hbuf, const int* __restrict__ adj,
    const void* __restrict__ a, const void* __restrict__ ba,
    void* __restrict__ out, const void* __restrict__ feat)
{
    const int isbf = detect_bf16((const unsigned int*)feat);
    const int n = blockIdx.x, wave = threadIdx.x >> 6, lane = threadIdx.x & 63;
    const int hh = blockIdx.y * 4 + wave;
    int nbr_reg = n;
    if (lane < DEG) nbr_reg = adj[n * DEG + lane];
    const int f0 = lane * 2;
    const float adst0 = rd_scalar(a, hh * 256 + f0, isbf);
    const float adst1 = rd_scalar(a, hh * 256 + f0 + 1, isbf);
    const float asrc0 = rd_scalar(a, hh * 256 + 128 + f0, isbf);
    const float asrc1 = rd_scalar(a, hh * 256 + 128 + f0 + 1, isbf);
    const float bav   = rd_scalar(ba, hh, isbf);
    const __hip_bfloat16* hb = hbuf + (size_t)hh * N_NODES * F_OUT;
    float v0[17], v1[17], red[18];
#pragma unroll
    for (int d = 0; d < 17; ++d) {
        int nb = __shfl(nbr_reg, d, 64);
        unsigned int pk = *(const unsigned int*)&hb[(size_t)nb * F_OUT + f0];
        v0[d] = bf2f((unsigned short)(pk & 0xffffu));
        v1[d] = bf2f((unsigned short)(pk >> 16));
        red[d] = v0[d] * asrc0 + v1[d] * asrc1;
    }
    red[17] = v0[16] * adst0 + v1[16] * adst1;
#pragma unroll
    for (int off = 1; off < 64; off <<= 1)
#pragma unroll
        for (int r = 0; r < 18; ++r) red[r] += __shfl_xor(red[r], off, 64);
    const float sd = red[17] + bav;
    float sc[17], mx = -1e30f;
#pragma unroll
    for (int d = 0; d < 17; ++d) {
        float s = sd + red[d];
        s = s > 0.f ? s : 0.2f * s;
        sc[d] = s; mx = fmaxf(mx, s);
    }
    float ssum = 0.f;
#pragma unroll
    for (int d = 0; d < 17; ++d) { sc[d] = __expf(sc[d] - mx); ssum += sc[d]; }
    const float inv = 1.f / ssum;
    float o0 = 0.f, o1 = 0.f;
#pragma unroll
    for (int d = 0; d < 17; ++d) { o0 += sc[d] * v0[d]; o1 += sc[d] * v1[d]; }
    o0 *= inv; o1 *= inv;
    const size_t oidx = (size_t)n * (NH * F_OUT) + hh * F_OUT + f0;
    if (isbf) {
        *(unsigned int*)&((unsigned short*)out)[oidx] =
            (unsigned int)f2bf(o0) | ((unsigned int)f2bf(o1) << 16);
    } else {
        float2 res; res.x = o0; res.y = o1;
        *(float2*)&((float*)out)[oidx] = res;
    }
}

// ---------------------------------------------------------------------------
// ws (tier A, 34.5 MiB — proven available in R5):
//   hbuf 16M | sdst 256K | ssrc 256K | featb 16M | Wt 2M
// ---------------------------------------------------------------------------
extern "C" void kernel_launch(void* const* d_in, const int* in_sizes, int n_in,
                              void* d_out, int out_size, void* d_ws, size_t ws_size,
                              hipStream_t stream)
{
    const void* feat = d_in[0];
    const int*  adj  = (const int*)d_in[1];
    const void* W    = d_in[2];
    const void* bW   = d_in[3];
    const void* a    = d_in[4];
    const void* ba   = d_in[5];

    char* ws = (char*)d_ws;
    __hip_bfloat16* hbuf = (__hip_bfloat16*)ws;
    const size_t HB = (size_t)NH * N_NODES * F_OUT * 2;       // 16 MiB
    const size_t SC = (size_t)NH * N_NODES * 4;               // 256 KiB
    float* sdst = (float*)(ws + HB);
    float* ssrc = (float*)(ws + HB + SC);
    unsigned short* featb = (unsigned short*)(ws + HB + 2 * SC);
    unsigned short* Wt    = featb + (size_t)N_NODES * F_IN;
    const size_t needA = HB + 2 * SC +
        ((size_t)N_NODES * F_IN + (size_t)NH * F_IN * F_OUT) * 2; // 34.5 MiB

    if (ws_size >= needA) {
        conv_feat<<<4096, 256, 0, stream>>>(feat, featb);
        transp_W<<<256, 256, 0, stream>>>(W, Wt, feat);
        gat_gemm2<<<dim3(64, 8), 256, 0, stream>>>(featb, Wt, feat, bW, a, ba,
                                                   hbuf, sdst, ssrc);
        gat_aggr3<<<8192, 256, 0, stream>>>((const unsigned short*)hbuf, adj,
                                            sdst, ssrc, feat, d_out);
    } else {
        gat_gemm_fb<<<dim3(64, 8), 256, 0, stream>>>(feat, W, bW, hbuf);
        gat_aggr_fb<<<dim3(8192, 2), 256, 0, stream>>>(hbuf, adj, a, ba, d_out, feat);
    }
}

// Round 7
// 153.103 us; speedup vs baseline: 1.5668x; 1.1194x over previous
//
#include <hip/hip_runtime.h>
#include <hip/hip_bf16.h>

#define N_NODES 8192
#define DEG     16
#define F_IN    1024
#define F_OUT   128
#define NH      8

typedef __bf16 bf16x8 __attribute__((ext_vector_type(8)));
typedef float  f32x4  __attribute__((ext_vector_type(4)));

__device__ __forceinline__ float bf2f(unsigned short u) {
    union { unsigned int i; float f; } v;
    v.i = ((unsigned int)u) << 16;
    return v.f;
}
__device__ __forceinline__ unsigned short f2bf(float f) {
    union { float f; unsigned int u; } v; v.f = f;
    unsigned int u = v.u + 0x7FFFu + ((v.u >> 16) & 1u);
    return (unsigned short)(u >> 16);
}
// Runtime dtype probe (validated R4/R5: fp32 world). Wave-uniform.
__device__ __forceinline__ int detect_bf16(const unsigned int* __restrict__ w) {
    int hits = 0;
#pragma unroll
    for (int i = 0; i < 64; ++i) {
        unsigned int x = w[i * 131 + 17];
        int e = (x >> 7) & 0xFF;
        hits += (e >= 100 && e <= 140) ? 1 : 0;
    }
    return hits > 32;
}
__device__ __forceinline__ float rd_scalar(const void* p, int idx, int isbf) {
    return isbf ? bf2f(((const unsigned short*)p)[idx]) : ((const float*)p)[idx];
}
// async global->LDS, 16B per lane; LDS dest = wave-uniform base + lane*16
__device__ __forceinline__ void gload16(const void* g, void* l) {
    __builtin_amdgcn_global_load_lds(
        (const __attribute__((address_space(1))) void*)g,
        (__attribute__((address_space(3))) void*)l, 16, 0, 0);
}

// ---------------------------------------------------------------------------
// prep_inputs (merged conv_feat + transp_W — one dispatch instead of two):
// blocks [0,4096): feat -> featb (bf16, 8 elems/thread)
// blocks [4096,4352): W[h][k][o] -> Wt[h][o][k] via 64x64 LDS tile
// ---------------------------------------------------------------------------
__global__ __launch_bounds__(256) void prep_inputs(
    const void* __restrict__ feat, const void* __restrict__ W,
    unsigned short* __restrict__ featb, unsigned short* __restrict__ Wt)
{
    const int isbf = detect_bf16((const unsigned int*)feat);
    if (blockIdx.x < 4096) {
        size_t i8 = ((size_t)blockIdx.x * 256 + threadIdx.x) * 8;
        if (isbf) {
            *(uint4*)(featb + i8) = ((const uint4*)feat)[i8 / 8];
        } else {
            const float* s = (const float*)feat + i8;
            float4 u0 = *(const float4*)s;
            float4 u1 = *(const float4*)(s + 4);
            unsigned short t[8] = { f2bf(u0.x), f2bf(u0.y), f2bf(u0.z), f2bf(u0.w),
                                    f2bf(u1.x), f2bf(u1.y), f2bf(u1.z), f2bf(u1.w) };
            *(uint4*)(featb + i8) = *(const uint4*)t;
        }
    } else {
        __shared__ float tile[64][65];
        const int bx = blockIdx.x - 4096;
        const int h  = bx >> 5;
        const int kt = (bx >> 1) & 15;
        const int ot = bx & 1;
        const int t  = threadIdx.x;
#pragma unroll
        for (int i = 0; i < 16; ++i) {
            int id = i * 256 + t, r = id >> 6, c = id & 63;
            tile[r][c] = rd_scalar(W, ((h * 1024 + kt * 64 + r) * 128) + ot * 64 + c, isbf);
        }
        __syncthreads();
#pragma unroll
        for (int i = 0; i < 16; ++i) {
            int id = i * 256 + t, oc = id >> 6, kc = id & 63;
            Wt[(size_t)(h * 128 + ot * 64 + oc) * 1024 + kt * 64 + kc] = f2bf(tile[kc][oc]);
        }
    }
}

// ---------------------------------------------------------------------------
// gat_gemm2: h = feat @ W[h] + bW[h], 128x128 tile, BK=64, global_load_lds
// staging, XOR-swizzled chunks (R6: bank conflicts == 0). Fused score
// epilogue (sdst = h.a_dst + ba, ssrc = h.a_src, fp32).
// ---------------------------------------------------------------------------
__global__ __launch_bounds__(256) void gat_gemm2(
    const unsigned short* __restrict__ featb,  // [N, F_IN] bf16
    const unsigned short* __restrict__ Wt,     // [H, F_OUT, F_IN] bf16
    const void* __restrict__ raw_feat,
    const void* __restrict__ bW, const void* __restrict__ a,
    const void* __restrict__ ba,
    __hip_bfloat16* __restrict__ hbuf,
    float* __restrict__ sdst, float* __restrict__ ssrc)
{
    const int rawbf = detect_bf16((const unsigned int*)raw_feat);

    const int h   = blockIdx.y;
    const int n0  = blockIdx.x * 128;
    const int tid = threadIdx.x;

    __shared__ __align__(16) unsigned short As[128 * 64];
    __shared__ __align__(16) unsigned short Bs[128 * 64];

    const int lane = tid & 63;
    const int wave = tid >> 6;
    const int quad = lane >> 4;
    const int l16  = lane & 15;
    const int sw   = l16 & 7;        // fragment-read swizzle key (= row&7)

    f32x4 acc[2][8];
#pragma unroll
    for (int i = 0; i < 2; ++i)
#pragma unroll
        for (int j = 0; j < 8; ++j) acc[i][j] = (f32x4)0.f;

    const unsigned short* wbase = Wt + (size_t)h * F_OUT * F_IN;

    for (int k0 = 0; k0 < F_IN; k0 += 64) {
#pragma unroll
        for (int t = 0; t < 4; ++t) {
            const int r0  = t * 32 + wave * 8;           // wave-uniform
            const int row = r0 + (lane >> 3);
            const int gc  = (lane & 7) ^ (row & 7);      // XOR swizzle
            gload16(&featb[(size_t)(n0 + row) * F_IN + k0 + gc * 8], &As[r0 * 64]);
            gload16(&wbase[(size_t)row * F_IN + k0 + gc * 8], &Bs[r0 * 64]);
        }
        __syncthreads();

#pragma unroll
        for (int ks = 0; ks < 2; ++ks) {
            const int kc = ks * 4 + quad;
            const int cs = (kc ^ sw) * 8;
            bf16x8 af[2], bfr[8];
#pragma unroll
            for (int rt = 0; rt < 2; ++rt)
                af[rt] = *(const bf16x8*)&As[(wave * 32 + rt * 16 + l16) * 64 + cs];
#pragma unroll
            for (int ct = 0; ct < 8; ++ct)
                bfr[ct] = *(const bf16x8*)&Bs[(ct * 16 + l16) * 64 + cs];
#pragma unroll
            for (int rt = 0; rt < 2; ++rt)
#pragma unroll
                for (int ct = 0; ct < 8; ++ct)
                    acc[rt][ct] = __builtin_amdgcn_mfma_f32_16x16x32_bf16(
                        af[rt], bfr[ct], acc[rt][ct], 0, 0, 0);
        }
        __syncthreads();
    }

    // h-tile store (D: col = lane&15, row = quad*4 + reg — m89/m91)
#pragma unroll
    for (int ct = 0; ct < 8; ++ct) {
        const int col = ct * 16 + l16;
        const float bwv = rd_scalar(bW, h * F_OUT + col, rawbf);
#pragma unroll
        for (int rt = 0; rt < 2; ++rt) {
            const int nrow = n0 + wave * 32 + rt * 16 + quad * 4;
            __hip_bfloat16* dst = hbuf + ((size_t)h * N_NODES + nrow) * F_OUT + col;
#pragma unroll
            for (int r = 0; r < 4; ++r)
                dst[(size_t)r * F_OUT] = __float2bfloat16(acc[rt][ct][r] + bwv);
        }
    }

    // fused scores: reduce row dot a_dst/a_src over l16
    float adst[8], asrc[8];
#pragma unroll
    for (int ct = 0; ct < 8; ++ct) {
        const int col = ct * 16 + l16;
        adst[ct] = rd_scalar(a, h * 256 + col, rawbf);
        asrc[ct] = rd_scalar(a, h * 256 + 128 + col, rawbf);
    }
    float pd[2][4] = {}, ps[2][4] = {};
#pragma unroll
    for (int rt = 0; rt < 2; ++rt)
#pragma unroll
        for (int ct = 0; ct < 8; ++ct)
#pragma unroll
            for (int r = 0; r < 4; ++r) {
                pd[rt][r] += acc[rt][ct][r] * adst[ct];
                ps[rt][r] += acc[rt][ct][r] * asrc[ct];
            }
#pragma unroll
    for (int off = 1; off < 16; off <<= 1)
#pragma unroll
        for (int rt = 0; rt < 2; ++rt)
#pragma unroll
            for (int r = 0; r < 4; ++r) {
                pd[rt][r] += __shfl_xor(pd[rt][r], off, 64);
                ps[rt][r] += __shfl_xor(ps[rt][r], off, 64);
            }
    if (l16 == 0) {
        const float bav = rd_scalar(ba, h, rawbf);
#pragma unroll
        for (int rt = 0; rt < 2; ++rt) {
            const int base = n0 + wave * 32 + rt * 16 + quad * 4;
            float4 vd = { pd[rt][0] + bav, pd[rt][1] + bav,
                          pd[rt][2] + bav, pd[rt][3] + bav };
            float4 vs = { ps[rt][0], ps[rt][1], ps[rt][2], ps[rt][3] };
            *(float4*)&sdst[h * N_NODES + base] = vd;
            *(float4*)&ssrc[h * N_NODES + base] = vs;
        }
    }
}

// ---------------------------------------------------------------------------
// gat_aggr4: XCD-pinned heads. blockIdx.x = head (8-wide, fastest dispatch
// dim -> XCD = head via %8 round-robin); blockIdx.y = node-group of 8.
// Each XCD then only touches its head's 2 MB hbuf slice -> fits 4 MB L2.
// Half-wave per node; softmax via shfl within 32-half; zero LDS/barriers.
// ---------------------------------------------------------------------------
__global__ __launch_bounds__(256) void gat_aggr4(
    const unsigned short* __restrict__ hbuf,   // [H, N, F_OUT] bf16
    const int* __restrict__ adj,
    const float* __restrict__ sdst, const float* __restrict__ ssrc,
    const void* __restrict__ raw_feat, void* __restrict__ out)
{
    const int isbf = detect_bf16((const unsigned int*)raw_feat);
    const int h    = blockIdx.x;               // head == XCD slot
    const int wave = threadIdx.x >> 6;
    const int lane = threadIdx.x & 63;
    const int half = lane >> 5;
    const int l32  = lane & 31;
    const int n    = blockIdx.y * 8 + wave * 2 + half;

    int nbr = n;                               // self edge is slot 16
    if (l32 < DEG) nbr = adj[n * DEG + l32];

    float s = -1e30f;
    if (l32 < 17) {
        float sv = sdst[h * N_NODES + n] + ssrc[h * N_NODES + nbr];
        s = sv > 0.f ? sv : 0.2f * sv;         // leaky_relu(0.2)
    }
    float m = s;
#pragma unroll
    for (int off = 1; off < 32; off <<= 1)     // xor stays within 32-half
        m = fmaxf(m, __shfl_xor(m, off, 64));
    float ev = (l32 < 17) ? __expf(s - m) : 0.f;
    float sum = ev;
#pragma unroll
    for (int off = 1; off < 32; off <<= 1)
        sum += __shfl_xor(sum, off, 64);
    ev *= (1.f / sum);                         // normalized alpha (lanes d<17)

    const unsigned short* hb = hbuf + (size_t)h * N_NODES * F_OUT;
    const int fc    = l32 * 4;
    const int sbase = half << 5;
    float a0 = 0.f, a1 = 0.f, a2 = 0.f, a3 = 0.f;
#pragma unroll
    for (int d = 0; d < 17; ++d) {
        const int   nb = __shfl(nbr, sbase + d, 64);
        const float av = __shfl(ev,  sbase + d, 64);
        uint2 pk = *(const uint2*)&hb[(size_t)nb * F_OUT + fc];
        a0 += av * bf2f((unsigned short)(pk.x & 0xffffu));
        a1 += av * bf2f((unsigned short)(pk.x >> 16));
        a2 += av * bf2f((unsigned short)(pk.y & 0xffffu));
        a3 += av * bf2f((unsigned short)(pk.y >> 16));
    }

    const size_t oidx = (size_t)n * (NH * F_OUT) + h * F_OUT + fc;
    if (isbf) {
        uint2 res;
        res.x = (unsigned int)f2bf(a0) | ((unsigned int)f2bf(a1) << 16);
        res.y = (unsigned int)f2bf(a2) | ((unsigned int)f2bf(a3) << 16);
        *(uint2*)&((unsigned short*)out)[oidx] = res;
    } else {
        float4 res = { a0, a1, a2, a3 };
        *(float4*)&((float*)out)[oidx] = res;
    }
}

// ---------------------------------------------------------------------------
// Fallback tier (R4-proven pair) — only if ws < 34.5 MiB (tier A proven in
// R5/R6 to run; kept for safety).
// ---------------------------------------------------------------------------
__global__ __launch_bounds__(256) void gat_gemm_fb(
    const void* __restrict__ feat, const void* __restrict__ W,
    const void* __restrict__ bW, __hip_bfloat16* __restrict__ hbuf)
{
    const int isbf = detect_bf16((const unsigned int*)feat);
    const int h = blockIdx.y, n0 = blockIdx.x * 128, tid = threadIdx.x;
    __shared__ __align__(16) unsigned short As[128][72];
    __shared__ __align__(16) unsigned short Bs[128][72];
    const int lane = tid & 63, wave = tid >> 6, quad = lane >> 4, l16 = lane & 15;
    f32x4 acc[2][8];
#pragma unroll
    for (int i = 0; i < 2; ++i)
#pragma unroll
        for (int j = 0; j < 8; ++j) acc[i][j] = (f32x4)0.f;
    for (int k0 = 0; k0 < F_IN; k0 += 64) {
        if (isbf) {
            const unsigned short* fbase = (const unsigned short*)feat + (size_t)n0 * F_IN;
            const unsigned short* wsrc  = (const unsigned short*)W +
                                          (size_t)h * F_IN * F_OUT + (size_t)k0 * F_OUT;
#pragma unroll
            for (int t = 0; t < 4; ++t) {
                int c = t * 256 + tid, row = c >> 3, kc = c & 7;
                *(uint4*)&As[row][kc * 8] = *(const uint4*)&fbase[row * F_IN + k0 + kc * 8];
            }
#pragma unroll
            for (int t = 0; t < 2; ++t) {
                int c = t * 256 + tid, kr2 = c >> 4, mm = c & 15, oc = mm * 8;
                uint4 w0 = *(const uint4*)&wsrc[(2 * kr2) * F_OUT + oc];
                uint4 w1 = *(const uint4*)&wsrc[(2 * kr2 + 1) * F_OUT + oc];
                const unsigned short* p0 = (const unsigned short*)&w0;
                const unsigned short* p1 = (const unsigned short*)&w1;
#pragma unroll
                for (int j = 0; j < 8; ++j) {
                    int i = (j + mm) & 7;
                    *(unsigned int*)&Bs[oc + i][2 * kr2] =
                        (unsigned int)p0[i] | ((unsigned int)p1[i] << 16);
                }
            }
        } else {
            const float* fbase = (const float*)feat + (size_t)n0 * F_IN;
            const float* wsrc  = (const float*)W +
                                 (size_t)h * F_IN * F_OUT + (size_t)k0 * F_OUT;
#pragma unroll
            for (int t = 0; t < 4; ++t) {
                int c = t * 256 + tid, row = c >> 3, kc = c & 7;
                const float* src = &fbase[row * F_IN + k0 + kc * 8];
                float4 u0 = *(const float4*)src, u1 = *(const float4*)(src + 4);
                unsigned short sh[8] = { f2bf(u0.x), f2bf(u0.y), f2bf(u0.z), f2bf(u0.w),
                                         f2bf(u1.x), f2bf(u1.y), f2bf(u1.z), f2bf(u1.w) };
                *(uint4*)&As[row][kc * 8] = *(const uint4*)sh;
            }
#pragma unroll
            for (int t = 0; t < 2; ++t) {
                int c = t * 256 + tid, kr2 = c >> 4, mm = c & 15, oc = mm * 8;
                const float* r0 = &wsrc[(2 * kr2) * F_OUT + oc];
                const float* r1 = &wsrc[(2 * kr2 + 1) * F_OUT + oc];
                float4 e0 = *(const float4*)r0, e1 = *(const float4*)(r0 + 4);
                float4 o0 = *(const float4*)r1, o1 = *(const float4*)(r1 + 4);
                unsigned short p0[8] = { f2bf(e0.x), f2bf(e0.y), f2bf(e0.z), f2bf(e0.w),
                                         f2bf(e1.x), f2bf(e1.y), f2bf(e1.z), f2bf(e1.w) };
                unsigned short p1[8] = { f2bf(o0.x), f2bf(o0.y), f2bf(o0.z), f2bf(o0.w),
                                         f2bf(o1.x), f2bf(o1.y), f2bf(o1.z), f2bf(o1.w) };
#pragma unroll
                for (int j = 0; j < 8; ++j) {
                    int i = (j + mm) & 7;
                    *(unsigned int*)&Bs[oc + i][2 * kr2] =
                        (unsigned int)p0[i] | ((unsigned int)p1[i] << 16);
                }
            }
        }
        __syncthreads();
#pragma unroll
        for (int ks = 0; ks < 2; ++ks) {
            const int kk = ks * 32 + quad * 8;
            bf16x8 af[2], bfr[8];
#pragma unroll
            for (int rt = 0; rt < 2; ++rt)
                af[rt] = *(const bf16x8*)&As[wave * 32 + rt * 16 + l16][kk];
#pragma unroll
            for (int ct = 0; ct < 8; ++ct)
                bfr[ct] = *(const bf16x8*)&Bs[ct * 16 + l16][kk];
#pragma unroll
            for (int rt = 0; rt < 2; ++rt)
#pragma unroll
                for (int ct = 0; ct < 8; ++ct)
                    acc[rt][ct] = __builtin_amdgcn_mfma_f32_16x16x32_bf16(
                        af[rt], bfr[ct], acc[rt][ct], 0, 0, 0);
        }
        __syncthreads();
    }
#pragma unroll
    for (int ct = 0; ct < 8; ++ct) {
        const int col = ct * 16 + l16;
        const float bwv = rd_scalar(bW, h * F_OUT + col, isbf);
#pragma unroll
        for (int rt = 0; rt < 2; ++rt) {
            const int nrow = n0 + wave * 32 + rt * 16 + quad * 4;
            __hip_bfloat16* dst = hbuf + ((size_t)h * N_NODES + nrow) * F_OUT + col;
#pragma unroll
            for (int r = 0; r < 4; ++r)
                dst[(size_t)r * F_OUT] = __float2bfloat16(acc[rt][ct][r] + bwv);
        }
    }
}

__global__ __launch_bounds__(256) void gat_aggr_fb(
    const __hip_bfloat16* __restrict__ hbuf, const int* __restrict__ adj,
    const void* __restrict__ a, const void* __restrict__ ba,
    void* __restrict__ out, const void* __restrict__ feat)
{
    const int isbf = detect_bf16((const unsigned int*)feat);
    const int n = blockIdx.x, wave = threadIdx.x >> 6, lane = threadIdx.x & 63;
    const int hh = blockIdx.y * 4 + wave;
    int nbr_reg = n;
    if (lane < DEG) nbr_reg = adj[n * DEG + lane];
    const int f0 = lane * 2;
    const float adst0 = rd_scalar(a, hh * 256 + f0, isbf);
    const float adst1 = rd_scalar(a, hh * 256 + f0 + 1, isbf);
    const float asrc0 = rd_scalar(a, hh * 256 + 128 + f0, isbf);
    const float asrc1 = rd_scalar(a, hh * 256 + 128 + f0 + 1, isbf);
    const float bav   = rd_scalar(ba, hh, isbf);
    const __hip_bfloat16* hb = hbuf + (size_t)hh * N_NODES * F_OUT;
    float v0[17], v1[17], red[18];
#pragma unroll
    for (int d = 0; d < 17; ++d) {
        int nb = __shfl(nbr_reg, d, 64);
        unsigned int pk = *(const unsigned int*)&hb[(size_t)nb * F_OUT + f0];
        v0[d] = bf2f((unsigned short)(pk & 0xffffu));
        v1[d] = bf2f((unsigned short)(pk >> 16));
        red[d] = v0[d] * asrc0 + v1[d] * asrc1;
    }
    red[17] = v0[16] * adst0 + v1[16] * adst1;
#pragma unroll
    for (int off = 1; off < 64; off <<= 1)
#pragma unroll
        for (int r = 0; r < 18; ++r) red[r] += __shfl_xor(red[r], off, 64);
    const float sd = red[17] + bav;
    float sc[17], mx = -1e30f;
#pragma unroll
    for (int d = 0; d < 17; ++d) {
        float s = sd + red[d];
        s = s > 0.f ? s : 0.2f * s;
        sc[d] = s; mx = fmaxf(mx, s);
    }
    float ssum = 0.f;
#pragma unroll
    for (int d = 0; d < 17; ++d) { sc[d] = __expf(sc[d] - mx); ssum += sc[d]; }
    const float inv = 1.f / ssum;
    float o0 = 0.f, o1 = 0.f;
#pragma unroll
    for (int d = 0; d < 17; ++d) { o0 += sc[d] * v0[d]; o1 += sc[d] * v1[d]; }
    o0 *= inv; o1 *= inv;
    const size_t oidx = (size_t)n * (NH * F_OUT) + hh * F_OUT + f0;
    if (isbf) {
        *(unsigned int*)&((unsigned short*)out)[oidx] =
            (unsigned int)f2bf(o0) | ((unsigned int)f2bf(o1) << 16);
    } else {
        float2 res; res.x = o0; res.y = o1;
        *(float2*)&((float*)out)[oidx] = res;
    }
}

// ---------------------------------------------------------------------------
// ws (tier A, 34.5 MiB — proven): hbuf 16M | sdst 256K | ssrc 256K |
// featb 16M | Wt 2M
// ---------------------------------------------------------------------------
extern "C" void kernel_launch(void* const* d_in, const int* in_sizes, int n_in,
                              void* d_out, int out_size, void* d_ws, size_t ws_size,
                              hipStream_t stream)
{
    const void* feat = d_in[0];
    const int*  adj  = (const int*)d_in[1];
    const void* W    = d_in[2];
    const void* bW   = d_in[3];
    const void* a    = d_in[4];
    const void* ba   = d_in[5];

    char* ws = (char*)d_ws;
    __hip_bfloat16* hbuf = (__hip_bfloat16*)ws;
    const size_t HB = (size_t)NH * N_NODES * F_OUT * 2;       // 16 MiB
    const size_t SC = (size_t)NH * N_NODES * 4;               // 256 KiB
    float* sdst = (float*)(ws + HB);
    float* ssrc = (float*)(ws + HB + SC);
    unsigned short* featb = (unsigned short*)(ws + HB + 2 * SC);
    unsigned short* Wt    = featb + (size_t)N_NODES * F_IN;
    const size_t needA = HB + 2 * SC +
        ((size_t)N_NODES * F_IN + (size_t)NH * F_IN * F_OUT) * 2; // 34.5 MiB

    if (ws_size >= needA) {
        prep_inputs<<<4352, 256, 0, stream>>>(feat, W, featb, Wt);
        gat_gemm2<<<dim3(64, 8), 256, 0, stream>>>(featb, Wt, feat, bW, a, ba,
                                                   hbuf, sdst, ssrc);
        gat_aggr4<<<dim3(8, 1024), 256, 0, stream>>>((const unsigned short*)hbuf,
                                                     adj, sdst, ssrc, feat, d_out);
    } else {
        gat_gemm_fb<<<dim3(64, 8), 256, 0, stream>>>(feat, W, bW, hbuf);
        gat_aggr_fb<<<dim3(8192, 2), 256, 0, stream>>>(hbuf, adj, a, ba, d_out, feat);
    }
}

// Round 8
// 149.874 us; speedup vs baseline: 1.6005x; 1.0215x over previous
//
#include <hip/hip_runtime.h>
#include <hip/hip_bf16.h>

#define N_NODES 8192
#define DEG     16
#define F_IN    1024
#define F_OUT   128
#define NH      8

typedef __bf16 bf16x8 __attribute__((ext_vector_type(8)));
typedef float  f32x4  __attribute__((ext_vector_type(4)));

__device__ __forceinline__ float bf2f(unsigned short u) {
    union { unsigned int i; float f; } v;
    v.i = ((unsigned int)u) << 16;
    return v.f;
}
__device__ __forceinline__ unsigned short f2bf(float f) {
    union { float f; unsigned int u; } v; v.f = f;
    unsigned int u = v.u + 0x7FFFu + ((v.u >> 16) & 1u);
    return (unsigned short)(u >> 16);
}
// Runtime dtype probe (validated R4-R7: fp32 world). Wave-uniform.
__device__ __forceinline__ int detect_bf16(const unsigned int* __restrict__ w) {
    int hits = 0;
#pragma unroll
    for (int i = 0; i < 64; ++i) {
        unsigned int x = w[i * 131 + 17];
        int e = (x >> 7) & 0xFF;
        hits += (e >= 100 && e <= 140) ? 1 : 0;
    }
    return hits > 32;
}
__device__ __forceinline__ float rd_scalar(const void* p, int idx, int isbf) {
    return isbf ? bf2f(((const unsigned short*)p)[idx]) : ((const float*)p)[idx];
}
// async global->LDS, 16B per lane; LDS dest = wave-uniform base + lane*16
__device__ __forceinline__ void gload16(const void* g, void* l) {
    __builtin_amdgcn_global_load_lds(
        (const __attribute__((address_space(1))) void*)g,
        (__attribute__((address_space(3))) void*)l, 16, 0, 0);
}

// ---------------------------------------------------------------------------
// prep_inputs: blocks [0,4096): feat -> featb bf16; [4096,4352): W -> Wt
// (transpose via 64x64 LDS tile).
// ---------------------------------------------------------------------------
__global__ __launch_bounds__(256) void prep_inputs(
    const void* __restrict__ feat, const void* __restrict__ W,
    unsigned short* __restrict__ featb, unsigned short* __restrict__ Wt)
{
    const int isbf = detect_bf16((const unsigned int*)feat);
    if (blockIdx.x < 4096) {
        size_t i8 = ((size_t)blockIdx.x * 256 + threadIdx.x) * 8;
        if (isbf) {
            *(uint4*)(featb + i8) = ((const uint4*)feat)[i8 / 8];
        } else {
            const float* s = (const float*)feat + i8;
            float4 u0 = *(const float4*)s;
            float4 u1 = *(const float4*)(s + 4);
            unsigned short t[8] = { f2bf(u0.x), f2bf(u0.y), f2bf(u0.z), f2bf(u0.w),
                                    f2bf(u1.x), f2bf(u1.y), f2bf(u1.z), f2bf(u1.w) };
            *(uint4*)(featb + i8) = *(const uint4*)t;
        }
    } else {
        __shared__ float tile[64][65];
        const int bx = blockIdx.x - 4096;
        const int h  = bx >> 5;
        const int kt = (bx >> 1) & 15;
        const int ot = bx & 1;
        const int t  = threadIdx.x;
#pragma unroll
        for (int i = 0; i < 16; ++i) {
            int id = i * 256 + t, r = id >> 6, c = id & 63;
            tile[r][c] = rd_scalar(W, ((h * 1024 + kt * 64 + r) * 128) + ot * 64 + c, isbf);
        }
        __syncthreads();
#pragma unroll
        for (int i = 0; i < 16; ++i) {
            int id = i * 256 + t, oc = id >> 6, kc = id & 63;
            Wt[(size_t)(h * 128 + ot * 64 + oc) * 1024 + kt * 64 + kc] = f2bf(tile[kc][oc]);
        }
    }
}

// ---------------------------------------------------------------------------
// gat_gemm3: h = feat @ W[h] + bW[h]. 128x128 tile, BK=128 as TWO 64-k
// sub-tiles staged per barrier pair -> halves barrier-drain count vs R6/R7.
// Occupancy is grid-capped at 2 blocks/CU (512 blocks), so the 64 KB LDS
// costs nothing (2x64 KB = 128 KB < 160 KB). global_load_lds staging,
// XOR-swizzled chunks (R6: SQ_LDS_BANK_CONFLICT == 0). Fused score epilogue.
// ---------------------------------------------------------------------------
__global__ __launch_bounds__(256) void gat_gemm3(
    const unsigned short* __restrict__ featb,  // [N, F_IN] bf16
    const unsigned short* __restrict__ Wt,     // [H, F_OUT, F_IN] bf16
    const void* __restrict__ raw_feat,
    const void* __restrict__ bW, const void* __restrict__ a,
    const void* __restrict__ ba,
    __hip_bfloat16* __restrict__ hbuf,
    float* __restrict__ sdst, float* __restrict__ ssrc)
{
    const int rawbf = detect_bf16((const unsigned int*)raw_feat);

    const int h   = blockIdx.y;
    const int n0  = blockIdx.x * 128;
    const int tid = threadIdx.x;

    __shared__ __align__(16) unsigned short As[2][128 * 64];   // 32 KB
    __shared__ __align__(16) unsigned short Bs[2][128 * 64];   // 32 KB

    const int lane = tid & 63;
    const int wave = tid >> 6;
    const int quad = lane >> 4;
    const int l16  = lane & 15;
    const int sw   = l16 & 7;        // fragment-read swizzle key (= row&7)

    f32x4 acc[2][8];
#pragma unroll
    for (int i = 0; i < 2; ++i)
#pragma unroll
        for (int j = 0; j < 8; ++j) acc[i][j] = (f32x4)0.f;

    const unsigned short* wbase = Wt + (size_t)h * F_OUT * F_IN;

    for (int k0 = 0; k0 < F_IN; k0 += 128) {
        // stage BOTH 64-k sub-tiles (A and B each 128x64) before one barrier
#pragma unroll
        for (int p = 0; p < 2; ++p) {
            const int kk0 = k0 + p * 64;
#pragma unroll
            for (int t = 0; t < 4; ++t) {
                const int r0  = t * 32 + wave * 8;           // wave-uniform
                const int row = r0 + (lane >> 3);
                const int gc  = (lane & 7) ^ (row & 7);      // XOR swizzle
                gload16(&featb[(size_t)(n0 + row) * F_IN + kk0 + gc * 8],
                        &As[p][r0 * 64]);
                gload16(&wbase[(size_t)row * F_IN + kk0 + gc * 8],
                        &Bs[p][r0 * 64]);
            }
        }
        __syncthreads();   // one drain for 128 k of staging

#pragma unroll
        for (int p = 0; p < 2; ++p) {
#pragma unroll
            for (int ks = 0; ks < 2; ++ks) {
                const int kc = ks * 4 + quad;
                const int cs = (kc ^ sw) * 8;
                bf16x8 af[2], bfr[8];
#pragma unroll
                for (int rt = 0; rt < 2; ++rt)
                    af[rt] = *(const bf16x8*)&As[p][(wave * 32 + rt * 16 + l16) * 64 + cs];
#pragma unroll
                for (int ct = 0; ct < 8; ++ct)
                    bfr[ct] = *(const bf16x8*)&Bs[p][(ct * 16 + l16) * 64 + cs];
#pragma unroll
                for (int rt = 0; rt < 2; ++rt)
#pragma unroll
                    for (int ct = 0; ct < 8; ++ct)
                        acc[rt][ct] = __builtin_amdgcn_mfma_f32_16x16x32_bf16(
                            af[rt], bfr[ct], acc[rt][ct], 0, 0, 0);
            }
        }
        __syncthreads();
    }

    // h-tile store (D: col = lane&15, row = quad*4 + reg — m89/m91)
#pragma unroll
    for (int ct = 0; ct < 8; ++ct) {
        const int col = ct * 16 + l16;
        const float bwv = rd_scalar(bW, h * F_OUT + col, rawbf);
#pragma unroll
        for (int rt = 0; rt < 2; ++rt) {
            const int nrow = n0 + wave * 32 + rt * 16 + quad * 4;
            __hip_bfloat16* dst = hbuf + ((size_t)h * N_NODES + nrow) * F_OUT + col;
#pragma unroll
            for (int r = 0; r < 4; ++r)
                dst[(size_t)r * F_OUT] = __float2bfloat16(acc[rt][ct][r] + bwv);
        }
    }

    // fused scores: reduce row dot a_dst/a_src over l16
    float adst[8], asrc[8];
#pragma unroll
    for (int ct = 0; ct < 8; ++ct) {
        const int col = ct * 16 + l16;
        adst[ct] = rd_scalar(a, h * 256 + col, rawbf);
        asrc[ct] = rd_scalar(a, h * 256 + 128 + col, rawbf);
    }
    float pd[2][4] = {}, ps[2][4] = {};
#pragma unroll
    for (int rt = 0; rt < 2; ++rt)
#pragma unroll
        for (int ct = 0; ct < 8; ++ct)
#pragma unroll
            for (int r = 0; r < 4; ++r) {
                pd[rt][r] += acc[rt][ct][r] * adst[ct];
                ps[rt][r] += acc[rt][ct][r] * asrc[ct];
            }
#pragma unroll
    for (int off = 1; off < 16; off <<= 1)
#pragma unroll
        for (int rt = 0; rt < 2; ++rt)
#pragma unroll
            for (int r = 0; r < 4; ++r) {
                pd[rt][r] += __shfl_xor(pd[rt][r], off, 64);
                ps[rt][r] += __shfl_xor(ps[rt][r], off, 64);
            }
    if (l16 == 0) {
        const float bav = rd_scalar(ba, h, rawbf);
#pragma unroll
        for (int rt = 0; rt < 2; ++rt) {
            const int base = n0 + wave * 32 + rt * 16 + quad * 4;
            float4 vd = { pd[rt][0] + bav, pd[rt][1] + bav,
                          pd[rt][2] + bav, pd[rt][3] + bav };
            float4 vs = { ps[rt][0], ps[rt][1], ps[rt][2], ps[rt][3] };
            *(float4*)&sdst[h * N_NODES + base] = vd;
            *(float4*)&ssrc[h * N_NODES + base] = vs;
        }
    }
}

// ---------------------------------------------------------------------------
// gat_aggr4: XCD-pinned heads (blockIdx.x = head -> XCD via %8 round-robin;
// R7: wall -18 µs). Each XCD touches only its head's 2 MB hbuf slice (L2-
// resident). Half-wave per (node, head); softmax via shfl within 32-half;
// zero LDS, zero barriers.
// ---------------------------------------------------------------------------
__global__ __launch_bounds__(256) void gat_aggr4(
    const unsigned short* __restrict__ hbuf,   // [H, N, F_OUT] bf16
    const int* __restrict__ adj,
    const float* __restrict__ sdst, const float* __restrict__ ssrc,
    const void* __restrict__ raw_feat, void* __restrict__ out)
{
    const int isbf = detect_bf16((const unsigned int*)raw_feat);
    const int h    = blockIdx.x;               // head == XCD slot
    const int wave = threadIdx.x >> 6;
    const int lane = threadIdx.x & 63;
    const int half = lane >> 5;
    const int l32  = lane & 31;
    const int n    = blockIdx.y * 8 + wave * 2 + half;

    int nbr = n;                               // self edge is slot 16
    if (l32 < DEG) nbr = adj[n * DEG + l32];

    float s = -1e30f;
    if (l32 < 17) {
        float sv = sdst[h * N_NODES + n] + ssrc[h * N_NODES + nbr];
        s = sv > 0.f ? sv : 0.2f * sv;         // leaky_relu(0.2)
    }
    float m = s;
#pragma unroll
    for (int off = 1; off < 32; off <<= 1)     // xor stays within 32-half
        m = fmaxf(m, __shfl_xor(m, off, 64));
    float ev = (l32 < 17) ? __expf(s - m) : 0.f;
    float sum = ev;
#pragma unroll
    for (int off = 1; off < 32; off <<= 1)
        sum += __shfl_xor(sum, off, 64);
    ev *= (1.f / sum);                         // normalized alpha (lanes d<17)

    const unsigned short* hb = hbuf + (size_t)h * N_NODES * F_OUT;
    const int fc    = l32 * 4;
    const int sbase = half << 5;
    float a0 = 0.f, a1 = 0.f, a2 = 0.f, a3 = 0.f;
#pragma unroll
    for (int d = 0; d < 17; ++d) {
        const int   nb = __shfl(nbr, sbase + d, 64);
        const float av = __shfl(ev,  sbase + d, 64);
        uint2 pk = *(const uint2*)&hb[(size_t)nb * F_OUT + fc];
        a0 += av * bf2f((unsigned short)(pk.x & 0xffffu));
        a1 += av * bf2f((unsigned short)(pk.x >> 16));
        a2 += av * bf2f((unsigned short)(pk.y & 0xffffu));
        a3 += av * bf2f((unsigned short)(pk.y >> 16));
    }

    const size_t oidx = (size_t)n * (NH * F_OUT) + h * F_OUT + fc;
    if (isbf) {
        uint2 res;
        res.x = (unsigned int)f2bf(a0) | ((unsigned int)f2bf(a1) << 16);
        res.y = (unsigned int)f2bf(a2) | ((unsigned int)f2bf(a3) << 16);
        *(uint2*)&((unsigned short*)out)[oidx] = res;
    } else {
        float4 res = { a0, a1, a2, a3 };
        *(float4*)&((float*)out)[oidx] = res;
    }
}

// ---------------------------------------------------------------------------
// Fallback tier (R4-proven pair) — only if ws < 34.5 MiB (ws measured 256 MiB
// via harness fill size; kept purely for safety).
// ---------------------------------------------------------------------------
__global__ __launch_bounds__(256) void gat_gemm_fb(
    const void* __restrict__ feat, const void* __restrict__ W,
    const void* __restrict__ bW, __hip_bfloat16* __restrict__ hbuf)
{
    const int isbf = detect_bf16((const unsigned int*)feat);
    const int h = blockIdx.y, n0 = blockIdx.x * 128, tid = threadIdx.x;
    __shared__ __align__(16) unsigned short As[128][72];
    __shared__ __align__(16) unsigned short Bs[128][72];
    const int lane = tid & 63, wave = tid >> 6, quad = lane >> 4, l16 = lane & 15;
    f32x4 acc[2][8];
#pragma unroll
    for (int i = 0; i < 2; ++i)
#pragma unroll
        for (int j = 0; j < 8; ++j) acc[i][j] = (f32x4)0.f;
    for (int k0 = 0; k0 < F_IN; k0 += 64) {
        if (isbf) {
            const unsigned short* fbase = (const unsigned short*)feat + (size_t)n0 * F_IN;
            const unsigned short* wsrc  = (const unsigned short*)W +
                                          (size_t)h * F_IN * F_OUT + (size_t)k0 * F_OUT;
#pragma unroll
            for (int t = 0; t < 4; ++t) {
                int c = t * 256 + tid, row = c >> 3, kc = c & 7;
                *(uint4*)&As[row][kc * 8] = *(const uint4*)&fbase[row * F_IN + k0 + kc * 8];
            }
#pragma unroll
            for (int t = 0; t < 2; ++t) {
                int c = t * 256 + tid, kr2 = c >> 4, mm = c & 15, oc = mm * 8;
                uint4 w0 = *(const uint4*)&wsrc[(2 * kr2) * F_OUT + oc];
                uint4 w1 = *(const uint4*)&wsrc[(2 * kr2 + 1) * F_OUT + oc];
                const unsigned short* p0 = (const unsigned short*)&w0;
                const unsigned short* p1 = (const unsigned short*)&w1;
#pragma unroll
                for (int j = 0; j < 8; ++j) {
                    int i = (j + mm) & 7;
                    *(unsigned int*)&Bs[oc + i][2 * kr2] =
                        (unsigned int)p0[i] | ((unsigned int)p1[i] << 16);
                }
            }
        } else {
            const float* fbase = (const float*)feat + (size_t)n0 * F_IN;
            const float* wsrc  = (const float*)W +
                                 (size_t)h * F_IN * F_OUT + (size_t)k0 * F_OUT;
#pragma unroll
            for (int t = 0; t < 4; ++t) {
                int c = t * 256 + tid, row = c >> 3, kc = c & 7;
                const float* src = &fbase[row * F_IN + k0 + kc * 8];
                float4 u0 = *(const float4*)src, u1 = *(const float4*)(src + 4);
                unsigned short sh[8] = { f2bf(u0.x), f2bf(u0.y), f2bf(u0.z), f2bf(u0.w),
                                         f2bf(u1.x), f2bf(u1.y), f2bf(u1.z), f2bf(u1.w) };
                *(uint4*)&As[row][kc * 8] = *(const uint4*)sh;
            }
#pragma unroll
            for (int t = 0; t < 2; ++t) {
                int c = t * 256 + tid, kr2 = c >> 4, mm = c & 15, oc = mm * 8;
                const float* r0 = &wsrc[(2 * kr2) * F_OUT + oc];
                const float* r1 = &wsrc[(2 * kr2 + 1) * F_OUT + oc];
                float4 e0 = *(const float4*)r0, e1 = *(const float4*)(r0 + 4);
                float4 o0 = *(const float4*)r1, o1 = *(const float4*)(r1 + 4);
                unsigned short p0[8] = { f2bf(e0.x), f2bf(e0.y), f2bf(e0.z), f2bf(e0.w),
                                         f2bf(e1.x), f2bf(e1.y), f2bf(e1.z), f2bf(e1.w) };
                unsigned short p1[8] = { f2bf(o0.x), f2bf(o0.y), f2bf(o0.z), f2bf(o0.w),
                                         f2bf(o1.x), f2bf(o1.y), f2bf(o1.z), f2bf(o1.w) };
#pragma unroll
                for (int j = 0; j < 8; ++j) {
                    int i = (j + mm) & 7;
                    *(unsigned int*)&Bs[oc + i][2 * kr2] =
                        (unsigned int)p0[i] | ((unsigned int)p1[i] << 16);
                }
            }
        }
        __syncthreads();
#pragma unroll
        for (int ks = 0; ks < 2; ++ks) {
            const int kk = ks * 32 + quad * 8;
            bf16x8 af[2], bfr[8];
#pragma unroll
            for (int rt = 0; rt < 2; ++rt)
                af[rt] = *(const bf16x8*)&As[wave * 32 + rt * 16 + l16][kk];
#pragma unroll
            for (int ct = 0; ct < 8; ++ct)
                bfr[ct] = *(const bf16x8*)&Bs[ct * 16 + l16][kk];
#pragma unroll
            for (int rt = 0; rt < 2; ++rt)
#pragma unroll
                for (int ct = 0; ct < 8; ++ct)
                    acc[rt][ct] = __builtin_amdgcn_mfma_f32_16x16x32_bf16(
                        af[rt], bfr[ct], acc[rt][ct], 0, 0, 0);
        }
        __syncthreads();
    }
#pragma unroll
    for (int ct = 0; ct < 8; ++ct) {
        const int col = ct * 16 + l16;
        const float bwv = rd_scalar(bW, h * F_OUT + col, isbf);
#pragma unroll
        for (int rt = 0; rt < 2; ++rt) {
            const int nrow = n0 + wave * 32 + rt * 16 + quad * 4;
            __hip_bfloat16* dst = hbuf + ((size_t)h * N_NODES + nrow) * F_OUT + col;
#pragma unroll
            for (int r = 0; r < 4; ++r)
                dst[(size_t)r * F_OUT] = __float2bfloat16(acc[rt][ct][r] + bwv);
        }
    }
}

__global__ __launch_bounds__(256) void gat_aggr_fb(
    const __hip_bfloat16* __restrict__ hbuf, const int* __restrict__ adj,
    const void* __restrict__ a, const void* __restrict__ ba,
    void* __restrict__ out, const void* __restrict__ feat)
{
    const int isbf = detect_bf16((const unsigned int*)feat);
    const int n = blockIdx.x, wave = threadIdx.x >> 6, lane = threadIdx.x & 63;
    const int hh = blockIdx.y * 4 + wave;
    int nbr_reg = n;
    if (lane < DEG) nbr_reg = adj[n * DEG + lane];
    const int f0 = lane * 2;
    const float adst0 = rd_scalar(a, hh * 256 + f0, isbf);
    const float adst1 = rd_scalar(a, hh * 256 + f0 + 1, isbf);
    const float asrc0 = rd_scalar(a, hh * 256 + 128 + f0, isbf);
    const float asrc1 = rd_scalar(a, hh * 256 + 128 + f0 + 1, isbf);
    const float bav   = rd_scalar(ba, hh, isbf);
    const __hip_bfloat16* hb = hbuf + (size_t)hh * N_NODES * F_OUT;
    float v0[17], v1[17], red[18];
#pragma unroll
    for (int d = 0; d < 17; ++d) {
        int nb = __shfl(nbr_reg, d, 64);
        unsigned int pk = *(const unsigned int*)&hb[(size_t)nb * F_OUT + f0];
        v0[d] = bf2f((unsigned short)(pk & 0xffffu));
        v1[d] = bf2f((unsigned short)(pk >> 16));
        red[d] = v0[d] * asrc0 + v1[d] * asrc1;
    }
    red[17] = v0[16] * adst0 + v1[16] * adst1;
#pragma unroll
    for (int off = 1; off < 64; off <<= 1)
#pragma unroll
        for (int r = 0; r < 18; ++r) red[r] += __shfl_xor(red[r], off, 64);
    const float sd = red[17] + bav;
    float sc[17], mx = -1e30f;
#pragma unroll
    for (int d = 0; d < 17; ++d) {
        float s = sd + red[d];
        s = s > 0.f ? s : 0.2f * s;
        sc[d] = s; mx = fmaxf(mx, s);
    }
    float ssum = 0.f;
#pragma unroll
    for (int d = 0; d < 17; ++d) { sc[d] = __expf(sc[d] - mx); ssum += sc[d]; }
    const float inv = 1.f / ssum;
    float o0 = 0.f, o1 = 0.f;
#pragma unroll
    for (int d = 0; d < 17; ++d) { o0 += sc[d] * v0[d]; o1 += sc[d] * v1[d]; }
    o0 *= inv; o1 *= inv;
    const size_t oidx = (size_t)n * (NH * F_OUT) + hh * F_OUT + f0;
    if (isbf) {
        *(unsigned int*)&((unsigned short*)out)[oidx] =
            (unsigned int)f2bf(o0) | ((unsigned int)f2bf(o1) << 16);
    } else {
        float2 res; res.x = o0; res.y = o1;
        *(float2*)&((float*)out)[oidx] = res;
    }
}

// ---------------------------------------------------------------------------
// ws (256 MiB measured via harness fill): hbuf 16M | sdst 256K | ssrc 256K |
// featb 16M | Wt 2M
// ---------------------------------------------------------------------------
extern "C" void kernel_launch(void* const* d_in, const int* in_sizes, int n_in,
                              void* d_out, int out_size, void* d_ws, size_t ws_size,
                              hipStream_t stream)
{
    const void* feat = d_in[0];
    const int*  adj  = (const int*)d_in[1];
    const void* W    = d_in[2];
    const void* bW   = d_in[3];
    const void* a    = d_in[4];
    const void* ba   = d_in[5];

    char* ws = (char*)d_ws;
    __hip_bfloat16* hbuf = (__hip_bfloat16*)ws;
    const size_t HB = (size_t)NH * N_NODES * F_OUT * 2;       // 16 MiB
    const size_t SC = (size_t)NH * N_NODES * 4;               // 256 KiB
    float* sdst = (float*)(ws + HB);
    float* ssrc = (float*)(ws + HB + SC);
    unsigned short* featb = (unsigned short*)(ws + HB + 2 * SC);
    unsigned short* Wt    = featb + (size_t)N_NODES * F_IN;
    const size_t needA = HB + 2 * SC +
        ((size_t)N_NODES * F_IN + (size_t)NH * F_IN * F_OUT) * 2; // 34.5 MiB

    if (ws_size >= needA) {
        prep_inputs<<<4352, 256, 0, stream>>>(feat, W, featb, Wt);
        gat_gemm3<<<dim3(64, 8), 256, 0, stream>>>(featb, Wt, feat, bW, a, ba,
                                                   hbuf, sdst, ssrc);
        gat_aggr4<<<dim3(8, 1024), 256, 0, stream>>>((const unsigned short*)hbuf,
                                                     adj, sdst, ssrc, feat, d_out);
    } else {
        gat_gemm_fb<<<dim3(64, 8), 256, 0, stream>>>(feat, W, bW, hbuf);
        gat_aggr_fb<<<dim3(8192, 2), 256, 0, stream>>>(hbuf, adj, a, ba, d_out, feat);
    }
}